// Round 10
// baseline (792.390 us; speedup 1.0000x reference)
//
#include <hip/hip_runtime.h>
#include <math.h>

#define BZ 256
#define NN 360
#define NP1 361
#define MROWS (BZ*NN)   // 92160
#define POOLL 252
#define KP 384          // padded K (12 tiles of 32)

typedef __attribute__((ext_vector_type(8))) short bf16x8;
typedef __attribute__((ext_vector_type(4))) float f32x4;

__device__ __forceinline__ float lrelu(float x){ return x > 0.f ? x : 0.2f*x; }

__device__ __forceinline__ ushort f2bf(float f){
    union { float f; uint u; } v; v.f = f;
    uint u = v.u + 0x7FFFu + ((v.u >> 16) & 1u);
    return (ushort)(u >> 16);
}
__device__ __forceinline__ float bf2f(ushort h){
    union { uint u; float f; } v; v.u = ((uint)h) << 16;
    return v.f;
}
__device__ __forceinline__ void split2(float v, ushort& hi, ushort& lo){
    hi = f2bf(v);
    lo = f2bf(v - bf2f(hi));
}

// async global->LDS, 16B per lane, dest = wave-uniform base + lane*16
__device__ __forceinline__ void gload16(const void* g, void* l){
    __builtin_amdgcn_global_load_lds((const __attribute__((address_space(1))) uint*)g,
                                     (__attribute__((address_space(3))) uint*)l, 16, 0, 0);
}

// stage one bf16 plane [128 rows x 32 cols] from src (row stride KP) into P with chunk swizzle
__device__ __forceinline__ void stage_plane(const ushort* __restrict__ src, size_t srow0,
                                            ushort (*P)[32], int k0, int t){
    int w = t >> 6;
    #pragma unroll
    for (int i=0;i<2;i++){
        int u = i*256 + t;
        int row = u >> 2, ccs = u & 3;
        int cg = ccs ^ ((row >> 1) & 3);
        const ushort* g = src + (srow0 + row)*KP + k0 + cg*8;
        char* l = (char*)P + i*4096 + w*1024;
        gload16(g, l);
    }
}

// fragment read from swizzled plane: logical (row, chunk g)
__device__ __forceinline__ bf16x8 frag_read(const ushort (*P)[32], int row, int g){
    return *(const bf16x8*)((const char*)P + row*64 + ((g ^ ((row >> 1) & 3)) * 16));
}

// ---------------- rowsum (+ stats zero): one wave per row, float4 ----------------
__global__ __launch_bounds__(256)
void k_rowsum(const float* __restrict__ m, float* __restrict__ rowsum, float* __restrict__ stats){
    int gi = blockIdx.x*blockDim.x + threadIdx.x;
    if (gi < 1472) stats[gi] = 0.f;
    int wid = gi >> 6;
    int lane = threadIdx.x & 63;
    if (wid >= MROWS) return;
    const float4* p = (const float4*)(m + (size_t)wid*NN);
    float s = 0.f;
    {
        float4 f = p[lane];
        s += f.x + f.y + f.z + f.w;
    }
    if (lane < 26){
        float4 f = p[64 + lane];
        s += f.x + f.y + f.z + f.w;
    }
    #pragma unroll
    for (int off = 32; off; off >>= 1) s += __shfl_down(s, off);
    if (lane == 0) rowsum[wid] = s;
}

// ---------------- weight prep ----------------
__global__ __launch_bounds__(384)
void k_prepw(const float* __restrict__ W, int ncols, int joff,
             const float* __restrict__ s, const float* __restrict__ h,
             ushort* __restrict__ Wth, ushort* __restrict__ Wtl, float* __restrict__ cvec)
{
    int j = blockIdx.x;
    int k = threadIdx.x;      // 0..383
    __shared__ float red[6];
    float wv = 0.f, hv = 0.f, sv = 1.f;
    if (k < NN && j < ncols){
        wv = W[(size_t)k*ncols + j];
        if (s) sv = s[k];
        if (h) hv = h[k];
    }
    ushort hi, lo; split2(wv * sv, hi, lo);
    Wth[(size_t)(joff + j)*KP + k] = hi;
    Wtl[(size_t)(joff + j)*KP + k] = lo;
    float v = hv * wv;
    #pragma unroll
    for (int off = 32; off; off >>= 1) v += __shfl_down(v, off);
    int lane = k & 63, wid = k >> 6;
    if (lane == 0) red[wid] = v;
    __syncthreads();
    if (k == 0) cvec[joff + j] = red[0]+red[1]+red[2]+red[3]+red[4]+red[5];
}

// ---------------- big MFMA GEMM, split-bf16 (3-term), 128x128 tile, global_load_lds staging ----------------
template<bool AF32, bool RESID>
__global__ __launch_bounds__(256)
void k_gemm_mfma(const void* __restrict__ Avh, const ushort* __restrict__ Avl,
                 const ushort* __restrict__ Wth, const ushort* __restrict__ Wtl,
                 const float* __restrict__ cvec, const float* __restrict__ bias,
                 const float* __restrict__ rowsum,
                 const float* __restrict__ bns, const float* __restrict__ bnh,
                 ushort* __restrict__ Yhi, ushort* __restrict__ Ylo,
                 float* __restrict__ colsum, float* __restrict__ colsq)
{
    __shared__ ushort Ah[128][32];
    __shared__ ushort Al[128][32];
    __shared__ ushort Bh[128][32];
    __shared__ ushort Bl[128][32];
    int t = threadIdx.x;
    int w = t >> 6, lane = t & 63;
    int l15 = lane & 15, g = lane >> 4;
    int idx = blockIdx.x;
    int gr = idx & 7;
    int rem = idx >> 3;
    int jcb = rem % 3;
    int gq = rem / 3;
    int rowblk = (gq*8 + gr) * 128;
    int colblk = jcb * 128;

    f32x4 acc[2][8];
    #pragma unroll
    for (int i=0;i<2;i++)
        #pragma unroll
        for (int j=0;j<8;j++)
            #pragma unroll
            for (int e=0;e<4;e++) acc[i][j][e] = 0.f;

    for (int kt = 0; kt < 12; ++kt){
        int k0 = kt * 32;
        if (AF32){
            const float* A = (const float*)Avh;
            int row = t >> 1, half = t & 1;
            int fr = (row >> 1) & 3;
            #pragma unroll
            for (int c=0;c<2;c++){
                int cg = half*2 + c;
                int k = k0 + cg*8;
                float4 f0 = make_float4(0.f,0.f,0.f,0.f);
                float4 f1 = make_float4(0.f,0.f,0.f,0.f);
                if (k < NN){
                    f0 = *(const float4*)&A[(size_t)(rowblk+row)*NN + k];
                    f1 = *(const float4*)&A[(size_t)(rowblk+row)*NN + k + 4];
                }
                ushort h0,l0,h1,l1,h2,l2,h3,l3,h4,l4,h5,l5,h6,l6,h7,l7;
                split2(f0.x,h0,l0); split2(f0.y,h1,l1); split2(f0.z,h2,l2); split2(f0.w,h3,l3);
                split2(f1.x,h4,l4); split2(f1.y,h5,l5); split2(f1.z,h6,l6); split2(f1.w,h7,l7);
                uint4 hv = make_uint4((uint)h0|((uint)h1<<16), (uint)h2|((uint)h3<<16),
                                      (uint)h4|((uint)h5<<16), (uint)h6|((uint)h7<<16));
                uint4 lv = make_uint4((uint)l0|((uint)l1<<16), (uint)l2|((uint)l3<<16),
                                      (uint)l4|((uint)l5<<16), (uint)l6|((uint)l7<<16));
                int ccs = cg ^ fr;
                *(uint4*)((char*)Ah + row*64 + ccs*16) = hv;
                *(uint4*)((char*)Al + row*64 + ccs*16) = lv;
            }
        } else {
            stage_plane((const ushort*)Avh, (size_t)rowblk, Ah, k0, t);
            stage_plane(Avl,               (size_t)rowblk, Al, k0, t);
        }
        stage_plane(Wth, (size_t)colblk, Bh, k0, t);
        stage_plane(Wtl, (size_t)colblk, Bl, k0, t);
        __syncthreads();

        bf16x8 ah0 = frag_read(Ah, 32*w + l15, g);
        bf16x8 ah1 = frag_read(Ah, 32*w + 16 + l15, g);
        bf16x8 al0 = frag_read(Al, 32*w + l15, g);
        bf16x8 al1 = frag_read(Al, 32*w + 16 + l15, g);
        #pragma unroll
        for (int nj=0;nj<8;nj++){
            bf16x8 bh = frag_read(Bh, 16*nj + l15, g);
            bf16x8 bl = frag_read(Bl, 16*nj + l15, g);
            acc[0][nj] = __builtin_amdgcn_mfma_f32_16x16x32_bf16(ah0, bh, acc[0][nj], 0, 0, 0);
            acc[0][nj] = __builtin_amdgcn_mfma_f32_16x16x32_bf16(al0, bh, acc[0][nj], 0, 0, 0);
            acc[0][nj] = __builtin_amdgcn_mfma_f32_16x16x32_bf16(ah0, bl, acc[0][nj], 0, 0, 0);
            acc[1][nj] = __builtin_amdgcn_mfma_f32_16x16x32_bf16(ah1, bh, acc[1][nj], 0, 0, 0);
            acc[1][nj] = __builtin_amdgcn_mfma_f32_16x16x32_bf16(al1, bh, acc[1][nj], 0, 0, 0);
            acc[1][nj] = __builtin_amdgcn_mfma_f32_16x16x32_bf16(ah1, bl, acc[1][nj], 0, 0, 0);
        }
        __syncthreads();
    }

    const ushort* AHg = (const ushort*)Avh;
    float cs_part[8] = {0,0,0,0,0,0,0,0}, cq_part[8] = {0,0,0,0,0,0,0,0};
    #pragma unroll
    for (int mi=0;mi<2;mi++){
        #pragma unroll
        for (int nj=0;nj<8;nj++){
            f32x4 d = acc[mi][nj];
            #pragma unroll
            for (int r=0;r<4;r++){
                int row = rowblk + 32*w + 16*mi + 4*g + r;
                int col = colblk + 16*nj + l15;
                float v = 0.f;
                if (col < NN){
                    float pre = rowsum[row] * (d[r] + cvec[col]) + bias[col];
                    v = lrelu(pre);
                    if (RESID){
                        size_t ai = (size_t)row*KP + col;
                        float ar = bf2f(AHg[ai]) + bf2f(Avl[ai]);
                        v += ar * bns[col] + bnh[col];
                    }
                }
                ushort hi, lo; split2(v, hi, lo);
                Yhi[(size_t)row*KP + col] = hi;
                Ylo[(size_t)row*KP + col] = lo;
                cs_part[nj] += v;
                cq_part[nj] += v*v;
            }
        }
    }
    #pragma unroll
    for (int nj=0;nj<8;nj++){
        cs_part[nj] += __shfl_xor(cs_part[nj], 16); cs_part[nj] += __shfl_xor(cs_part[nj], 32);
        cq_part[nj] += __shfl_xor(cq_part[nj], 16); cq_part[nj] += __shfl_xor(cq_part[nj], 32);
    }
    float* red = (float*)&Ah[0][0];      // 512 floats used
    if (lane < 16){
        #pragma unroll
        for (int nj=0;nj<8;nj++) red[w*128 + nj*16 + l15] = cs_part[nj];
    }
    __syncthreads();
    if (t < 128 && colblk + t < NN)
        atomicAdd(&colsum[colblk + t], red[t] + red[128+t] + red[256+t] + red[384+t]);
    __syncthreads();
    if (lane < 16){
        #pragma unroll
        for (int nj=0;nj<8;nj++) red[w*128 + nj*16 + l15] = cq_part[nj];
    }
    __syncthreads();
    if (t < 128 && colblk + t < NN)
        atomicAdd(&colsq[colblk + t], red[t] + red[128+t] + red[256+t] + red[384+t]);
}

// ---------------- BN finalize ----------------
__global__ void k_bnfin(const float* __restrict__ colsum, const float* __restrict__ colsq,
                        const float* __restrict__ g, const float* __restrict__ b, int ncols,
                        float* __restrict__ scale, float* __restrict__ shift){
    int j = blockIdx.x*blockDim.x + threadIdx.x;
    if (j >= ncols) return;
    float mu = colsum[j] / (float)MROWS;
    float var = colsq[j] / (float)MROWS - mu*mu;
    float sc = g[j] * rsqrtf(var + 1e-5f);
    scale[j] = sc;
    shift[j] = b[j] - mu*sc;
}

// ---------------- gemm2 fused with stage2: y1 @ Wt2 -> h1/sc in LDS -> x2 + BN2 stats ----------------
__global__ __launch_bounds__(256)
void k_gemm2_fused(const ushort* __restrict__ AH, const ushort* __restrict__ AL,
                   const ushort* __restrict__ Wth, const ushort* __restrict__ Wtl,
                   const float* __restrict__ cvec, const float* __restrict__ b1,
                   const float* __restrict__ scb, const float* __restrict__ rowsum,
                   const float* __restrict__ w2, const float* __restrict__ b2,
                   float* __restrict__ x2, float* __restrict__ colsum, float* __restrict__ colsq)
{
    __shared__ __align__(16) char smem[46848];
    ushort (*Ah)[32] = (ushort(*)[32])smem;
    ushort (*Al)[32] = (ushort(*)[32])(smem + 8192);
    ushort (*Bh)[40] = (ushort(*)[40])(smem + 16384);
    ushort (*Bl)[40] = (ushort(*)[40])(smem + 16384 + 6400);

    int t = threadIdx.x;
    int w = t >> 6, lane = t & 63;
    int l15 = lane & 15, g = lane >> 4;
    int rowblk = blockIdx.x * 128;

    f32x4 acc[2][5];
    #pragma unroll
    for (int i=0;i<2;i++)
        #pragma unroll
        for (int j=0;j<5;j++)
            #pragma unroll
            for (int e=0;e<4;e++) acc[i][j][e] = 0.f;

    for (int kt = 0; kt < 12; ++kt){
        int k0 = kt * 32;
        stage_plane(AH, (size_t)rowblk, Ah, k0, t);
        stage_plane(AL, (size_t)rowblk, Al, k0, t);
        #pragma unroll
        for (int l=0;l<2;l++){
            int c = t + l*256;
            if (c < 320){
                int col = c >> 2, kk = (c & 3)*8;
                ((int4*)&Bh[col][kk])[0] = *(const int4*)&Wth[(size_t)col*KP + k0 + kk];
                ((int4*)&Bl[col][kk])[0] = *(const int4*)&Wtl[(size_t)col*KP + k0 + kk];
            }
        }
        __syncthreads();
        bf16x8 ah0 = frag_read(Ah, 32*w + l15, g);
        bf16x8 ah1 = frag_read(Ah, 32*w + 16 + l15, g);
        bf16x8 al0 = frag_read(Al, 32*w + l15, g);
        bf16x8 al1 = frag_read(Al, 32*w + 16 + l15, g);
        #pragma unroll
        for (int nj=0;nj<5;nj++){
            bf16x8 bh = *(const bf16x8*)&Bh[16*nj + l15][8*g];
            bf16x8 bl = *(const bf16x8*)&Bl[16*nj + l15][8*g];
            acc[0][nj] = __builtin_amdgcn_mfma_f32_16x16x32_bf16(ah0, bh, acc[0][nj], 0, 0, 0);
            acc[0][nj] = __builtin_amdgcn_mfma_f32_16x16x32_bf16(al0, bh, acc[0][nj], 0, 0, 0);
            acc[0][nj] = __builtin_amdgcn_mfma_f32_16x16x32_bf16(ah0, bl, acc[0][nj], 0, 0, 0);
            acc[1][nj] = __builtin_amdgcn_mfma_f32_16x16x32_bf16(ah1, bh, acc[1][nj], 0, 0, 0);
            acc[1][nj] = __builtin_amdgcn_mfma_f32_16x16x32_bf16(al1, bh, acc[1][nj], 0, 0, 0);
            acc[1][nj] = __builtin_amdgcn_mfma_f32_16x16x32_bf16(ah1, bl, acc[1][nj], 0, 0, 0);
        }
        __syncthreads();
    }

    // epilogue: h1/sc -> LDS (union over staging), then x2 = lrelu(h1@w2+b2)+sc + BN2 stats
    float (*Hs)[65] = (float(*)[65])smem;                 // 128 x 65 f32 = 33280 B
    float (*Sc)[16] = (float(*)[16])(smem + 33280);       // 128 x 16 f32 = 8192 B
    float (*Ws)[17] = (float(*)[17])(smem + 41472);       // 64 x 17 f32  = 4352 B (uses [16] cols)
    #pragma unroll
    for (int mi=0;mi<2;mi++){
        #pragma unroll
        for (int nj=0;nj<5;nj++){
            f32x4 d = acc[mi][nj];
            #pragma unroll
            for (int r=0;r<4;r++){
                int lrow = 32*w + 16*mi + 4*g + r;
                int row = rowblk + lrow;
                int col = 16*nj + l15;
                if (nj < 4){
                    float pre = rowsum[row] * (d[r] + cvec[col]) + b1[col];
                    Hs[lrow][col] = lrelu(pre);
                } else {
                    Sc[lrow][col-64] = lrelu(d[r] + cvec[col] + scb[col-64]);
                }
            }
        }
    }
    #pragma unroll
    for (int l=0;l<4;l++){
        int i2 = t + l*256;
        Ws[i2>>4][i2&15] = w2[i2];
    }
    __syncthreads();

    int col = t & 15, rb = t >> 4;
    float ps = 0.f, pq = 0.f;
    #pragma unroll
    for (int gg=0; gg<8; gg++){
        int r = rb + gg*16;
        float s = b2[col];
        #pragma unroll
        for (int c=0;c<64;c++) s += Hs[r][c]*Ws[c][col];
        float v = lrelu(s) + Sc[r][col];
        x2[(size_t)(rowblk+r)*16 + col] = v;
        ps += v; pq += v*v;
    }
    __syncthreads();
    float (*red)[16] = (float(*)[16])smem;
    red[rb][col] = ps; __syncthreads();
    if (t < 16){
        float s = 0.f;
        for (int g2=0; g2<16; g2++) s += red[g2][t];
        atomicAdd(&colsum[t], s);
    }
    __syncthreads();
    red[rb][col] = pq; __syncthreads();
    if (t < 16){
        float s = 0.f;
        for (int g2=0; g2<16; g2++) s += red[g2][t];
        atomicAdd(&colsq[t], s);
    }
}

// ---------------- QKV precompute: qkv[b][tensor][r][32] (q pre-scaled, biases folded) ----------------
__global__ __launch_bounds__(256)
void k_qkv(const float* __restrict__ x2, const float* __restrict__ s2, const float* __restrict__ h2,
           const float* __restrict__ cls,
           const float* __restrict__ wq, const float* __restrict__ bq,
           const float* __restrict__ wk, const float* __restrict__ bk,
           const float* __restrict__ wv, const float* __restrict__ bv,
           float* __restrict__ qkv)
{
    int b = blockIdx.x;
    __shared__ float4 xin[NP1][4];
    int t = threadIdx.x;
    for (int i = t; i < NP1*4; i += 256){
        int r = i >> 2, c4 = i & 3;
        float4 f;
        if (r == 0) f = ((const float4*)cls)[c4];
        else {
            f = *(const float4*)&x2[((size_t)b*NN + r-1)*16 + c4*4];
            f.x = f.x*s2[c4*4+0] + h2[c4*4+0];
            f.y = f.y*s2[c4*4+1] + h2[c4*4+1];
            f.z = f.z*s2[c4*4+2] + h2[c4*4+2];
            f.w = f.w*s2[c4*4+3] + h2[c4*4+3];
        }
        xin[r][c4] = f;
    }
    __syncthreads();
    for (int task = t; task < 3*NP1*8; task += 256){
        int tn = task / (NP1*8);
        int rem = task - tn*(NP1*8);
        int r = rem >> 3, d4 = rem & 7;
        const float* W  = (tn==0) ? wq : ((tn==1) ? wk : wv);
        const float* Bb = (tn==0) ? bq : ((tn==1) ? bk : bv);
        float o0 = Bb[d4*4+0], o1 = Bb[d4*4+1], o2 = Bb[d4*4+2], o3 = Bb[d4*4+3];
        #pragma unroll
        for (int c4=0;c4<4;c4++){
            float4 xf = xin[r][c4];
            float xs[4] = {xf.x, xf.y, xf.z, xf.w};
            #pragma unroll
            for (int cc=0;cc<4;cc++){
                int c = c4*4 + cc;
                float x = xs[cc];
                o0 += x * W[c*32 + d4*4 + 0];
                o1 += x * W[c*32 + d4*4 + 1];
                o2 += x * W[c*32 + d4*4 + 2];
                o3 += x * W[c*32 + d4*4 + 3];
            }
        }
        if (tn == 0){
            const float sc = 0.35355339059327373f;
            o0 *= sc; o1 *= sc; o2 *= sc; o3 *= sc;
        }
        *(float4*)&qkv[(((size_t)b*3 + tn)*NP1 + r)*32 + d4*4] = make_float4(o0,o1,o2,o3);
    }
}

// ---------------- butterfly: reduce o[8] over 64 lanes; lane<8 returns sum for d=((l&1)<<2)|(l&2)|((l>>2)&1) ----------------
__device__ __forceinline__ float bfly8(float o[8], int lane){
    int b0 = lane & 1, b1 = lane & 2, b2 = lane & 4;
    float n[4];
    #pragma unroll
    for (int j=0;j<4;j++){
        float give = b0 ? o[j] : o[j+4];
        float keep = b0 ? o[j+4] : o[j];
        n[j] = keep + __shfl_xor(give, 1);
    }
    float m2[2];
    #pragma unroll
    for (int j=0;j<2;j++){
        float give = b1 ? n[j] : n[j+2];
        float keep = b1 ? n[j+2] : n[j];
        m2[j] = keep + __shfl_xor(give, 2);
    }
    float give = b2 ? m2[0] : m2[1];
    float keep = b2 ? m2[1] : m2[0];
    float v = keep + __shfl_xor(give, 4);
    v += __shfl_xor(v, 8);
    v += __shfl_xor(v, 16);
    v += __shfl_xor(v, 32);
    return v;
}

// ---------------- attention: K/V in LDS->regs; q via uniform global loads (L2 broadcast) ----------------
__global__ __launch_bounds__(256)
void k_attn(const float* __restrict__ qkv, float* __restrict__ attn, float* __restrict__ obuf)
{
    int blk = blockIdx.x;
    int chunk = blk & 1;
    int bh = blk >> 1;
    int b = bh >> 2, h = bh & 3;
    __shared__ float4 KV[4][NP1];   // [kA(d0-3), kB(d4-7), vA, vB][row]
    int t = threadIdx.x;

    const float* qb = qkv + ((size_t)b*3 + 0)*NP1*32 + h*8;
    const float* kb = qkv + ((size_t)b*3 + 1)*NP1*32 + h*8;
    const float* vb = qkv + ((size_t)b*3 + 2)*NP1*32 + h*8;
    for (int i = t; i < NP1*4; i += 256){
        int r = i >> 2, s = i & 3;
        int dq = s & 1;
        const float* src = (s < 2) ? kb : vb;
        KV[(s < 2 ? 0 : 2) + dq][r] = *(const float4*)&src[(size_t)r*32 + dq*4];
    }
    __syncthreads();

    int w = t >> 6, lane = t & 63;
    float kreg[6][8], vreg[6][8];
    #pragma unroll
    for (int j=0;j<6;j++){
        int ki = lane + (j<<6);
        int kc = ki > 360 ? 360 : ki;
        float4 ka = KV[0][kc], kb2 = KV[1][kc];
        float4 va = KV[2][kc], vb2 = KV[3][kc];
        kreg[j][0]=ka.x; kreg[j][1]=ka.y; kreg[j][2]=ka.z; kreg[j][3]=ka.w;
        kreg[j][4]=kb2.x; kreg[j][5]=kb2.y; kreg[j][6]=kb2.z; kreg[j][7]=kb2.w;
        vreg[j][0]=va.x; vreg[j][1]=va.y; vreg[j][2]=va.z; vreg[j][3]=va.w;
        vreg[j][4]=vb2.x; vreg[j][5]=vb2.y; vreg[j][6]=vb2.z; vreg[j][7]=vb2.w;
    }

    int cbase = chunk * 181;
    int cend  = chunk ? NP1 : 181;

    for (int qi0 = cbase + (w<<1); qi0 < cend; qi0 += 8){
        int qi1 = qi0 + 1;
        bool v1 = (qi1 < cend);
        int q1r = v1 ? qi1 : qi0;

        float q0[8], q1[8];
        {
            float4 a  = *(const float4*)&qb[(size_t)qi0*32];
            float4 c  = *(const float4*)&qb[(size_t)qi0*32 + 4];
            float4 a1 = *(const float4*)&qb[(size_t)q1r*32];
            float4 c1 = *(const float4*)&qb[(size_t)q1r*32 + 4];
            q0[0]=a.x;q0[1]=a.y;q0[2]=a.z;q0[3]=a.w;q0[4]=c.x;q0[5]=c.y;q0[6]=c.z;q0[7]=c.w;
            q1[0]=a1.x;q1[1]=a1.y;q1[2]=a1.z;q1[3]=a1.w;q1[4]=c1.x;q1[5]=c1.y;q1[6]=c1.z;q1[7]=c1.w;
        }

        float e0[6], e1[6];
        float mx0 = -1e30f, mx1 = -1e30f;
        #pragma unroll
        for (int j=0;j<6;j++){
            int ki = lane + (j<<6);
            float s0 = 0.f, s1 = 0.f;
            #pragma unroll
            for (int d=0;d<8;d++){ s0 += q0[d]*kreg[j][d]; s1 += q1[d]*kreg[j][d]; }
            if (ki >= NP1){ s0 = -1e30f; s1 = -1e30f; }
            e0[j] = s0; e1[j] = s1;
            mx0 = fmaxf(mx0, s0); mx1 = fmaxf(mx1, s1);
        }
        #pragma unroll
        for (int off=32; off; off>>=1){
            mx0 = fmaxf(mx0, __shfl_xor(mx0, off));
            mx1 = fmaxf(mx1, __shfl_xor(mx1, off));
        }
        float sum0 = 0.f, sum1 = 0.f;
        #pragma unroll
        for (int j=0;j<6;j++){
            float p0 = __expf(e0[j]-mx0);
            float p1 = __expf(e1[j]-mx1);
            e0[j]=p0; e1[j]=p1;
            sum0 += p0; sum1 += p1;
        }
        #pragma unroll
        for (int off=32; off; off>>=1){
            sum0 += __shfl_xor(sum0, off);
            sum1 += __shfl_xor(sum1, off);
        }
        float inv0 = 1.f/sum0;
        float inv1 = 1.f/sum1;

        size_t abase = (size_t)bh*NP1*NP1 + (size_t)qi0*NP1;
        float o0[8] = {0,0,0,0,0,0,0,0};
        float o1[8] = {0,0,0,0,0,0,0,0};
        #pragma unroll
        for (int j=0;j<6;j++){
            int ki = lane + (j<<6);
            float p0 = e0[j]*inv0;
            float p1 = e1[j]*inv1;
            if (ki < NP1){
                attn[abase + ki] = p0;
                if (v1) attn[abase + NP1 + ki] = p1;
            }
            #pragma unroll
            for (int d=0;d<8;d++){
                o0[d] += p0*vreg[j][d];
                o1[d] += p1*vreg[j][d];
            }
        }
        float val0 = bfly8(o0, lane);
        float val1 = bfly8(o1, lane);
        int l7 = lane & 7;
        int dmap = ((l7&1)<<2) | (l7&2) | ((l7>>2)&1);
        if (lane < 8)
            obuf[((size_t)b*NP1 + qi0)*32 + h*8 + dmap] = val0;
        else if (lane < 16 && v1)
            obuf[((size_t)b*NP1 + qi1)*32 + h*8 + dmap] = val1;
    }
}

// ---------------- score + sigmoid + top-k select + softmax pool + MLP head ----------------
__global__ __launch_bounds__(256)
void k_pool(const float* __restrict__ attn, const float* __restrict__ obuf,
            const float* __restrict__ wo, const float* __restrict__ bo,
            const float* __restrict__ f1w, const float* __restrict__ f1b,
            const float* __restrict__ f2w, const float* __restrict__ f2b,
            const float* __restrict__ f3w, const float* __restrict__ f3b,
            float* __restrict__ out_sig, float* __restrict__ logits)
{
    int b = blockIdx.x;
    __shared__ float sc[NN];
    __shared__ float w[NN];
    __shared__ float red[256];
    __shared__ float pooled32[32];
    __shared__ float p16[16];
    __shared__ float h64[64];
    __shared__ float h32[32];
    int t = threadIdx.x;
    for (int i=t; i<NN; i+=256){
        float s = 0.f;
        #pragma unroll
        for (int h=0; h<4; h++)
            s += attn[(((size_t)b*4+h)*NP1)*NP1 + 1 + i];
        sc[i] = s;
        out_sig[b*NN + i] = 1.f/(1.f + __expf(-s));
    }
    __syncthreads();
    float mx = -1e30f;
    for (int i=t; i<NN; i+=256) mx = fmaxf(mx, sc[i]);
    red[t] = mx; __syncthreads();
    for (int s=128; s; s>>=1){ if (t<s) red[t]=fmaxf(red[t],red[t+s]); __syncthreads(); }
    mx = red[0];
    __syncthreads();
    float psum = 0.f;
    for (int i=t; i<NN; i+=256){
        float si = sc[i];
        int r = 0;
        for (int j=0;j<NN;j++){
            float sj = sc[j];
            r += (sj > si) || (sj == si && j < i);
        }
        float wi = (r < POOLL) ? __expf(si - mx) : 0.f;
        w[i] = wi;
        psum += wi;
    }
    red[t] = psum; __syncthreads();
    for (int s=128; s; s>>=1){ if (t<s) red[t]+=red[t+s]; __syncthreads(); }
    float inv = 1.f / red[0];
    __syncthreads();
    if (t < 32){
        float s = 0.f;
        for (int i=0;i<NN;i++) s += w[i] * obuf[((size_t)b*NP1 + 1 + i)*32 + t];
        pooled32[t] = s * inv;
    }
    __syncthreads();
    if (t < 16){
        float s = bo[t];
        for (int d=0;d<32;d++) s += pooled32[d]*wo[d*16+t];
        p16[t] = s;
    }
    __syncthreads();
    if (t < 64){
        float s = f1b[t];
        for (int c=0;c<16;c++) s += p16[c]*f1w[c*64+t];
        h64[t] = lrelu(s);
    }
    __syncthreads();
    if (t < 32){
        float s = f2b[t];
        for (int c=0;c<64;c++) s += h64[c]*f2w[c*32+t];
        h32[t] = lrelu(s);
    }
    __syncthreads();
    if (t < 2){
        float s = f3b[t];
        for (int c=0;c<32;c++) s += h32[c]*f3w[c*2+t];
        logits[b*2+t] = s;
    }
}

extern "C" void kernel_launch(void* const* d_in, const int* in_sizes, int n_in,
                              void* d_out, int out_size, void* d_ws, size_t ws_size,
                              hipStream_t stream)
{
    const float* m    = (const float*)d_in[0];
    const float* nf   = (const float*)d_in[1];
    const float* cls  = (const float*)d_in[2];
    const float* g0w  = (const float*)d_in[3];
    const float* g0b  = (const float*)d_in[4];
    const float* g1w  = (const float*)d_in[5];
    const float* g1b  = (const float*)d_in[6];
    const float* g2w1 = (const float*)d_in[7];
    const float* g2b1 = (const float*)d_in[8];
    const float* g2w2 = (const float*)d_in[9];
    const float* g2b2 = (const float*)d_in[10];
    const float* scw  = (const float*)d_in[11];
    const float* scb  = (const float*)d_in[12];
    const float* bn0g = (const float*)d_in[13];
    const float* bn0b = (const float*)d_in[14];
    const float* bn1g = (const float*)d_in[15];
    const float* bn1b = (const float*)d_in[16];
    const float* bn2g = (const float*)d_in[17];
    const float* bn2b = (const float*)d_in[18];
    const float* wq = (const float*)d_in[19];
    const float* bq = (const float*)d_in[20];
    const float* wk = (const float*)d_in[21];
    const float* bk = (const float*)d_in[22];
    const float* wv = (const float*)d_in[23];
    const float* bv = (const float*)d_in[24];
    const float* wo = (const float*)d_in[25];
    const float* bo = (const float*)d_in[26];
    const float* f1w = (const float*)d_in[27];
    const float* f1b = (const float*)d_in[28];
    const float* f2w = (const float*)d_in[29];
    const float* f2b = (const float*)d_in[30];
    const float* f3w = (const float*)d_in[31];
    const float* f3b = (const float*)d_in[32];

    float* out_logits = (float*)d_out;
    float* out_sig = out_logits + 512;
    float* attn = out_sig + (size_t)BZ*NN;

    // big scratch inside the attn output region (dead until k_attn writes it)
    char* base = (char*)attn;
    const size_t szy = (size_t)MROWS * KP * 2;            // bf16 plane
    ushort* y0h = (ushort*)base;
    ushort* y0l = (ushort*)(base + szy);
    ushort* y1h = (ushort*)(base + 2*szy);
    ushort* y1l = (ushort*)(base + 3*szy);
    ushort* Wt0h = (ushort*)(base + 4*szy);
    ushort* Wt0l = Wt0h + (size_t)KP*KP;
    ushort* Wt1h = Wt0l + (size_t)KP*KP;
    ushort* Wt1l = Wt1h + (size_t)KP*KP;
    ushort* Wt2h = Wt1l + (size_t)KP*KP;
    ushort* Wt2l = Wt2h + (size_t)KP*KP;
    float*  c0  = (float*)(Wt2l + (size_t)KP*KP);
    float*  c1  = c0 + KP;
    float*  c2  = c1 + KP;

    float* ws = (float*)d_ws;
    float* rowsum = ws;                ws += MROWS;
    float* stats  = ws;                ws += 1472;
    float* cs0 = stats, *cq0 = stats+360, *cs1 = stats+720, *cq1 = stats+1080,
         * cs2 = stats+1440, *cq2 = stats+1456;
    float* s0 = ws;  ws += 360;
    float* h0 = ws;  ws += 360;
    float* s1 = ws;  ws += 360;
    float* hh1 = ws; ws += 360;
    float* s2 = ws;  ws += 16;
    float* h2 = ws;  ws += 16;
    float* x2 = ws;       ws += (size_t)MROWS*16;
    float* obuf = ws;     ws += (size_t)BZ*NP1*32;
    float* qkv = ws;      ws += (size_t)BZ*3*NP1*32;

    k_rowsum<<<MROWS/4, 256, 0, stream>>>(m, rowsum, stats);
    k_prepw<<<KP, KP, 0, stream>>>(g0w, 360, 0, nullptr, nullptr, Wt0h, Wt0l, c0);

    k_gemm_mfma<true,false><<<2160, 256, 0, stream>>>(nf, nullptr, Wt0h, Wt0l, c0, g0b, rowsum, nullptr, nullptr, y0h, y0l, cs0, cq0);
    k_bnfin<<<1, 384, 0, stream>>>(cs0, cq0, bn0g, bn0b, 360, s0, h0);
    k_prepw<<<KP, KP, 0, stream>>>(g1w, 360, 0, s0, h0, Wt1h, Wt1l, c1);
    k_gemm_mfma<false,true><<<2160, 256, 0, stream>>>(y0h, y0l, Wt1h, Wt1l, c1, g1b, rowsum, s0, h0, y1h, y1l, cs1, cq1);
    k_bnfin<<<1, 384, 0, stream>>>(cs1, cq1, bn1g, bn1b, 360, s1, hh1);
    k_prepw<<<64, KP, 0, stream>>>(g2w1, 64, 0, s1, hh1, Wt2h, Wt2l, c2);
    k_prepw<<<16, KP, 0, stream>>>(scw, 16, 64, s1, hh1, Wt2h, Wt2l, c2);
    k_gemm2_fused<<<720, 256, 0, stream>>>(y1h, y1l, Wt2h, Wt2l, c2, g2b1, scb, rowsum, g2w2, g2b2, x2, cs2, cq2);
    k_bnfin<<<1, 64, 0, stream>>>(cs2, cq2, bn2g, bn2b, 16, s2, h2);
    k_qkv<<<BZ, 256, 0, stream>>>(x2, s2, h2, cls, wq, bq, wk, bk, wv, bv, qkv);
    k_attn<<<BZ*4*2, 256, 0, stream>>>(qkv, attn, obuf);
    k_pool<<<BZ, 256, 0, stream>>>(attn, obuf, wo, bo, f1w, f1b, f2w, f2b, f3w, f3b, out_sig, out_logits);
}

// Round 11
// 741.984 us; speedup vs baseline: 1.0679x; 1.0679x over previous
//
#include <hip/hip_runtime.h>
#include <math.h>

#define BZ 256
#define NN 360
#define NP1 361
#define MROWS (BZ*NN)   // 92160
#define POOLL 252
#define KP 384          // padded K (12 tiles of 32)

typedef __attribute__((ext_vector_type(8))) short bf16x8;
typedef __attribute__((ext_vector_type(4))) float f32x4;

__device__ __forceinline__ float lrelu(float x){ return x > 0.f ? x : 0.2f*x; }

__device__ __forceinline__ ushort f2bf(float f){
    union { float f; uint u; } v; v.f = f;
    uint u = v.u + 0x7FFFu + ((v.u >> 16) & 1u);
    return (ushort)(u >> 16);
}
__device__ __forceinline__ float bf2f(ushort h){
    union { uint u; float f; } v; v.u = ((uint)h) << 16;
    return v.f;
}
__device__ __forceinline__ void split2(float v, ushort& hi, ushort& lo){
    hi = f2bf(v);
    lo = f2bf(v - bf2f(hi));
}

// async global->LDS, 16B per lane, dest = wave-uniform base + lane*16
__device__ __forceinline__ void gload16(const void* g, void* l){
    __builtin_amdgcn_global_load_lds((const __attribute__((address_space(1))) uint*)g,
                                     (__attribute__((address_space(3))) uint*)l, 16, 0, 0);
}

// stage one bf16 plane [128 rows x 32 cols] from src (row stride KP) into P with chunk swizzle
__device__ __forceinline__ void stage_plane(const ushort* __restrict__ src, size_t srow0,
                                            ushort (*P)[32], int k0, int t){
    int w = t >> 6;
    #pragma unroll
    for (int i=0;i<2;i++){
        int u = i*256 + t;
        int row = u >> 2, ccs = u & 3;
        int cg = ccs ^ ((row >> 1) & 3);
        const ushort* g = src + (srow0 + row)*KP + k0 + cg*8;
        char* l = (char*)P + i*4096 + w*1024;
        gload16(g, l);
    }
}

// fragment read from swizzled plane: logical (row, chunk g)
__device__ __forceinline__ bf16x8 frag_read(const ushort (*P)[32], int row, int g){
    return *(const bf16x8*)((const char*)P + row*64 + ((g ^ ((row >> 1) & 3)) * 16));
}

// ---------------- rowsum (+ stats zero): one wave per row, float4 ----------------
__global__ __launch_bounds__(256)
void k_rowsum(const float* __restrict__ m, float* __restrict__ rowsum, float* __restrict__ stats){
    int gi = blockIdx.x*blockDim.x + threadIdx.x;
    if (gi < 1472) stats[gi] = 0.f;
    int wid = gi >> 6;
    int lane = threadIdx.x & 63;
    if (wid >= MROWS) return;
    const float4* p = (const float4*)(m + (size_t)wid*NN);
    float s = 0.f;
    {
        float4 f = p[lane];
        s += f.x + f.y + f.z + f.w;
    }
    if (lane < 26){
        float4 f = p[64 + lane];
        s += f.x + f.y + f.z + f.w;
    }
    #pragma unroll
    for (int off = 32; off; off >>= 1) s += __shfl_down(s, off);
    if (lane == 0) rowsum[wid] = s;
}

// ---------------- weight prep ----------------
__global__ __launch_bounds__(384)
void k_prepw(const float* __restrict__ W, int ncols, int joff,
             const float* __restrict__ s, const float* __restrict__ h,
             ushort* __restrict__ Wth, ushort* __restrict__ Wtl, float* __restrict__ cvec)
{
    int j = blockIdx.x;
    int k = threadIdx.x;      // 0..383
    __shared__ float red[6];
    float wv = 0.f, hv = 0.f, sv = 1.f;
    if (k < NN && j < ncols){
        wv = W[(size_t)k*ncols + j];
        if (s) sv = s[k];
        if (h) hv = h[k];
    }
    ushort hi, lo; split2(wv * sv, hi, lo);
    Wth[(size_t)(joff + j)*KP + k] = hi;
    Wtl[(size_t)(joff + j)*KP + k] = lo;
    float v = hv * wv;
    #pragma unroll
    for (int off = 32; off; off >>= 1) v += __shfl_down(v, off);
    int lane = k & 63, wid = k >> 6;
    if (lane == 0) red[wid] = v;
    __syncthreads();
    if (k == 0) cvec[joff + j] = red[0]+red[1]+red[2]+red[3]+red[4]+red[5];
}

// ---------------- big MFMA GEMM, split-bf16 (3-term), 128x128 tile, global_load_lds staging ----------------
template<bool AF32, bool RESID>
__global__ __launch_bounds__(256)
void k_gemm_mfma(const void* __restrict__ Avh, const ushort* __restrict__ Avl,
                 const ushort* __restrict__ Wth, const ushort* __restrict__ Wtl,
                 const float* __restrict__ cvec, const float* __restrict__ bias,
                 const float* __restrict__ rowsum,
                 const float* __restrict__ bns, const float* __restrict__ bnh,
                 ushort* __restrict__ Yhi, ushort* __restrict__ Ylo,
                 float* __restrict__ colsum, float* __restrict__ colsq)
{
    __shared__ ushort Ah[128][32];
    __shared__ ushort Al[128][32];
    __shared__ ushort Bh[128][32];
    __shared__ ushort Bl[128][32];
    int t = threadIdx.x;
    int w = t >> 6, lane = t & 63;
    int l15 = lane & 15, g = lane >> 4;
    int idx = blockIdx.x;
    int gr = idx & 7;
    int rem = idx >> 3;
    int jcb = rem % 3;
    int gq = rem / 3;
    int rowblk = (gq*8 + gr) * 128;
    int colblk = jcb * 128;

    f32x4 acc[2][8];
    #pragma unroll
    for (int i=0;i<2;i++)
        #pragma unroll
        for (int j=0;j<8;j++)
            #pragma unroll
            for (int e=0;e<4;e++) acc[i][j][e] = 0.f;

    for (int kt = 0; kt < 12; ++kt){
        int k0 = kt * 32;
        if (AF32){
            const float* A = (const float*)Avh;
            int row = t >> 1, half = t & 1;
            int fr = (row >> 1) & 3;
            #pragma unroll
            for (int c=0;c<2;c++){
                int cg = half*2 + c;
                int k = k0 + cg*8;
                float4 f0 = make_float4(0.f,0.f,0.f,0.f);
                float4 f1 = make_float4(0.f,0.f,0.f,0.f);
                if (k < NN){
                    f0 = *(const float4*)&A[(size_t)(rowblk+row)*NN + k];
                    f1 = *(const float4*)&A[(size_t)(rowblk+row)*NN + k + 4];
                }
                ushort h0,l0,h1,l1,h2,l2,h3,l3,h4,l4,h5,l5,h6,l6,h7,l7;
                split2(f0.x,h0,l0); split2(f0.y,h1,l1); split2(f0.z,h2,l2); split2(f0.w,h3,l3);
                split2(f1.x,h4,l4); split2(f1.y,h5,l5); split2(f1.z,h6,l6); split2(f1.w,h7,l7);
                uint4 hv = make_uint4((uint)h0|((uint)h1<<16), (uint)h2|((uint)h3<<16),
                                      (uint)h4|((uint)h5<<16), (uint)h6|((uint)h7<<16));
                uint4 lv = make_uint4((uint)l0|((uint)l1<<16), (uint)l2|((uint)l3<<16),
                                      (uint)l4|((uint)l5<<16), (uint)l6|((uint)l7<<16));
                int ccs = cg ^ fr;
                *(uint4*)((char*)Ah + row*64 + ccs*16) = hv;
                *(uint4*)((char*)Al + row*64 + ccs*16) = lv;
            }
        } else {
            stage_plane((const ushort*)Avh, (size_t)rowblk, Ah, k0, t);
            stage_plane(Avl,               (size_t)rowblk, Al, k0, t);
        }
        stage_plane(Wth, (size_t)colblk, Bh, k0, t);
        stage_plane(Wtl, (size_t)colblk, Bl, k0, t);
        __syncthreads();

        bf16x8 ah0 = frag_read(Ah, 32*w + l15, g);
        bf16x8 ah1 = frag_read(Ah, 32*w + 16 + l15, g);
        bf16x8 al0 = frag_read(Al, 32*w + l15, g);
        bf16x8 al1 = frag_read(Al, 32*w + 16 + l15, g);
        #pragma unroll
        for (int nj=0;nj<8;nj++){
            bf16x8 bh = frag_read(Bh, 16*nj + l15, g);
            bf16x8 bl = frag_read(Bl, 16*nj + l15, g);
            acc[0][nj] = __builtin_amdgcn_mfma_f32_16x16x32_bf16(ah0, bh, acc[0][nj], 0, 0, 0);
            acc[0][nj] = __builtin_amdgcn_mfma_f32_16x16x32_bf16(al0, bh, acc[0][nj], 0, 0, 0);
            acc[0][nj] = __builtin_amdgcn_mfma_f32_16x16x32_bf16(ah0, bl, acc[0][nj], 0, 0, 0);
            acc[1][nj] = __builtin_amdgcn_mfma_f32_16x16x32_bf16(ah1, bh, acc[1][nj], 0, 0, 0);
            acc[1][nj] = __builtin_amdgcn_mfma_f32_16x16x32_bf16(al1, bh, acc[1][nj], 0, 0, 0);
            acc[1][nj] = __builtin_amdgcn_mfma_f32_16x16x32_bf16(ah1, bl, acc[1][nj], 0, 0, 0);
        }
        __syncthreads();
    }

    const ushort* AHg = (const ushort*)Avh;
    float cs_part[8] = {0,0,0,0,0,0,0,0}, cq_part[8] = {0,0,0,0,0,0,0,0};
    #pragma unroll
    for (int mi=0;mi<2;mi++){
        #pragma unroll
        for (int nj=0;nj<8;nj++){
            f32x4 d = acc[mi][nj];
            #pragma unroll
            for (int r=0;r<4;r++){
                int row = rowblk + 32*w + 16*mi + 4*g + r;
                int col = colblk + 16*nj + l15;
                float v = 0.f;
                if (col < NN){
                    float pre = rowsum[row] * (d[r] + cvec[col]) + bias[col];
                    v = lrelu(pre);
                    if (RESID){
                        size_t ai = (size_t)row*KP + col;
                        float ar = bf2f(AHg[ai]) + bf2f(Avl[ai]);
                        v += ar * bns[col] + bnh[col];
                    }
                }
                ushort hi, lo; split2(v, hi, lo);
                Yhi[(size_t)row*KP + col] = hi;
                Ylo[(size_t)row*KP + col] = lo;
                cs_part[nj] += v;
                cq_part[nj] += v*v;
            }
        }
    }
    #pragma unroll
    for (int nj=0;nj<8;nj++){
        cs_part[nj] += __shfl_xor(cs_part[nj], 16); cs_part[nj] += __shfl_xor(cs_part[nj], 32);
        cq_part[nj] += __shfl_xor(cq_part[nj], 16); cq_part[nj] += __shfl_xor(cq_part[nj], 32);
    }
    float* red = (float*)&Ah[0][0];      // 512 floats used
    if (lane < 16){
        #pragma unroll
        for (int nj=0;nj<8;nj++) red[w*128 + nj*16 + l15] = cs_part[nj];
    }
    __syncthreads();
    if (t < 128 && colblk + t < NN)
        atomicAdd(&colsum[colblk + t], red[t] + red[128+t] + red[256+t] + red[384+t]);
    __syncthreads();
    if (lane < 16){
        #pragma unroll
        for (int nj=0;nj<8;nj++) red[w*128 + nj*16 + l15] = cq_part[nj];
    }
    __syncthreads();
    if (t < 128 && colblk + t < NN)
        atomicAdd(&colsq[colblk + t], red[t] + red[128+t] + red[256+t] + red[384+t]);
}

// ---------------- BN finalize ----------------
__global__ void k_bnfin(const float* __restrict__ colsum, const float* __restrict__ colsq,
                        const float* __restrict__ g, const float* __restrict__ b, int ncols,
                        float* __restrict__ scale, float* __restrict__ shift){
    int j = blockIdx.x*blockDim.x + threadIdx.x;
    if (j >= ncols) return;
    float mu = colsum[j] / (float)MROWS;
    float var = colsq[j] / (float)MROWS - mu*mu;
    float sc = g[j] * rsqrtf(var + 1e-5f);
    scale[j] = sc;
    shift[j] = b[j] - mu*sc;
}

// ---------------- gemm2: A via global_load_lds (swizzled), B reg-staged padded ----------------
__global__ __launch_bounds__(256)
void k_gemm2_mfma(const ushort* __restrict__ AH, const ushort* __restrict__ AL,
                  const ushort* __restrict__ Wth, const ushort* __restrict__ Wtl,
                  const float* __restrict__ cvec, const float* __restrict__ b1,
                  const float* __restrict__ scb, const float* __restrict__ rowsum,
                  float* __restrict__ h1buf, float* __restrict__ scbuf)
{
    __shared__ ushort Ah[128][32];
    __shared__ ushort Al[128][32];
    __shared__ ushort Bh[80][40];
    __shared__ ushort Bl[80][40];
    int t = threadIdx.x;
    int w = t >> 6, lane = t & 63;
    int l15 = lane & 15, g = lane >> 4;
    int rowblk = blockIdx.x * 128;

    f32x4 acc[2][5];
    #pragma unroll
    for (int i=0;i<2;i++)
        #pragma unroll
        for (int j=0;j<5;j++)
            #pragma unroll
            for (int e=0;e<4;e++) acc[i][j][e] = 0.f;

    for (int kt = 0; kt < 12; ++kt){
        int k0 = kt * 32;
        stage_plane(AH, (size_t)rowblk, Ah, k0, t);
        stage_plane(AL, (size_t)rowblk, Al, k0, t);
        #pragma unroll
        for (int l=0;l<2;l++){
            int c = t + l*256;
            if (c < 320){
                int col = c >> 2, kk = (c & 3)*8;
                ((int4*)&Bh[col][kk])[0] = *(const int4*)&Wth[(size_t)col*KP + k0 + kk];
                ((int4*)&Bl[col][kk])[0] = *(const int4*)&Wtl[(size_t)col*KP + k0 + kk];
            }
        }
        __syncthreads();
        bf16x8 ah0 = frag_read(Ah, 32*w + l15, g);
        bf16x8 ah1 = frag_read(Ah, 32*w + 16 + l15, g);
        bf16x8 al0 = frag_read(Al, 32*w + l15, g);
        bf16x8 al1 = frag_read(Al, 32*w + 16 + l15, g);
        #pragma unroll
        for (int nj=0;nj<5;nj++){
            bf16x8 bh = *(const bf16x8*)&Bh[16*nj + l15][8*g];
            bf16x8 bl = *(const bf16x8*)&Bl[16*nj + l15][8*g];
            acc[0][nj] = __builtin_amdgcn_mfma_f32_16x16x32_bf16(ah0, bh, acc[0][nj], 0, 0, 0);
            acc[0][nj] = __builtin_amdgcn_mfma_f32_16x16x32_bf16(al0, bh, acc[0][nj], 0, 0, 0);
            acc[0][nj] = __builtin_amdgcn_mfma_f32_16x16x32_bf16(ah0, bl, acc[0][nj], 0, 0, 0);
            acc[1][nj] = __builtin_amdgcn_mfma_f32_16x16x32_bf16(ah1, bh, acc[1][nj], 0, 0, 0);
            acc[1][nj] = __builtin_amdgcn_mfma_f32_16x16x32_bf16(al1, bh, acc[1][nj], 0, 0, 0);
            acc[1][nj] = __builtin_amdgcn_mfma_f32_16x16x32_bf16(ah1, bl, acc[1][nj], 0, 0, 0);
        }
        __syncthreads();
    }

    #pragma unroll
    for (int mi=0;mi<2;mi++){
        #pragma unroll
        for (int nj=0;nj<5;nj++){
            f32x4 d = acc[mi][nj];
            #pragma unroll
            for (int r=0;r<4;r++){
                int row = rowblk + 32*w + 16*mi + 4*g + r;
                int col = 16*nj + l15;
                if (nj < 4){
                    float pre = rowsum[row] * (d[r] + cvec[col]) + b1[col];
                    h1buf[(size_t)row*64 + col] = lrelu(pre);
                } else {
                    int cc = col - 64;
                    float pre = d[r] + cvec[col] + scb[cc];
                    scbuf[(size_t)row*16 + cc] = lrelu(pre);
                }
            }
        }
    }
}

// ---------------- stage2 ----------------
__global__ __launch_bounds__(256)
void k_stage2(const float* __restrict__ h1buf, const float* __restrict__ scbuf,
              const float* __restrict__ w2, const float* __restrict__ b2,
              float* __restrict__ x2, float* __restrict__ colsum, float* __restrict__ colsq)
{
    __shared__ float Hs[64][65];
    __shared__ float Ws[64][17];
    __shared__ float red[16][16];
    int t = threadIdx.x;
    int rowblk = blockIdx.x * 64;
    #pragma unroll
    for (int l=0;l<4;l++){
        int idx = t + l*256;
        Ws[idx>>4][idx&15] = w2[idx];
    }
    #pragma unroll
    for (int l=0;l<16;l++){
        int idx = t + l*256;
        Hs[idx>>6][idx&63] = h1buf[(size_t)rowblk*64 + idx];
    }
    __syncthreads();
    int col = t & 15, rb = t >> 4;
    float ps=0.f, pq=0.f;
    #pragma unroll
    for (int gg=0; gg<4; gg++){
        int r = rb + gg*16;
        float s = b2[col];
        #pragma unroll
        for (int c=0;c<64;c++) s += Hs[r][c]*Ws[c][col];
        float v = lrelu(s) + scbuf[(size_t)(rowblk+r)*16 + col];
        x2[(size_t)(rowblk+r)*16 + col] = v;
        ps += v; pq += v*v;
    }
    red[rb][col] = ps; __syncthreads();
    if (t < 16){
        float s=0.f;
        for (int g=0; g<16; g++) s += red[g][t];
        atomicAdd(&colsum[t], s);
    }
    __syncthreads();
    red[rb][col] = pq; __syncthreads();
    if (t < 16){
        float s=0.f;
        for (int g=0; g<16; g++) s += red[g][t];
        atomicAdd(&colsq[t], s);
    }
}

// ---------------- QKV precompute: qkv[b][tensor][r][32] (q pre-scaled, biases folded) ----------------
__global__ __launch_bounds__(256)
void k_qkv(const float* __restrict__ x2, const float* __restrict__ s2, const float* __restrict__ h2,
           const float* __restrict__ cls,
           const float* __restrict__ wq, const float* __restrict__ bq,
           const float* __restrict__ wk, const float* __restrict__ bk,
           const float* __restrict__ wv, const float* __restrict__ bv,
           float* __restrict__ qkv)
{
    int b = blockIdx.x;
    __shared__ float4 xin[NP1][4];
    int t = threadIdx.x;
    for (int i = t; i < NP1*4; i += 256){
        int r = i >> 2, c4 = i & 3;
        float4 f;
        if (r == 0) f = ((const float4*)cls)[c4];
        else {
            f = *(const float4*)&x2[((size_t)b*NN + r-1)*16 + c4*4];
            f.x = f.x*s2[c4*4+0] + h2[c4*4+0];
            f.y = f.y*s2[c4*4+1] + h2[c4*4+1];
            f.z = f.z*s2[c4*4+2] + h2[c4*4+2];
            f.w = f.w*s2[c4*4+3] + h2[c4*4+3];
        }
        xin[r][c4] = f;
    }
    __syncthreads();
    for (int task = t; task < 3*NP1*8; task += 256){
        int tn = task / (NP1*8);
        int rem = task - tn*(NP1*8);
        int r = rem >> 3, d4 = rem & 7;
        const float* W  = (tn==0) ? wq : ((tn==1) ? wk : wv);
        const float* Bb = (tn==0) ? bq : ((tn==1) ? bk : bv);
        float o0 = Bb[d4*4+0], o1 = Bb[d4*4+1], o2 = Bb[d4*4+2], o3 = Bb[d4*4+3];
        #pragma unroll
        for (int c4=0;c4<4;c4++){
            float4 xf = xin[r][c4];
            float xs[4] = {xf.x, xf.y, xf.z, xf.w};
            #pragma unroll
            for (int cc=0;cc<4;cc++){
                int c = c4*4 + cc;
                float x = xs[cc];
                o0 += x * W[c*32 + d4*4 + 0];
                o1 += x * W[c*32 + d4*4 + 1];
                o2 += x * W[c*32 + d4*4 + 2];
                o3 += x * W[c*32 + d4*4 + 3];
            }
        }
        if (tn == 0){
            const float sc = 0.35355339059327373f;
            o0 *= sc; o1 *= sc; o2 *= sc; o3 *= sc;
        }
        *(float4*)&qkv[(((size_t)b*3 + tn)*NP1 + r)*32 + d4*4] = make_float4(o0,o1,o2,o3);
    }
}

// ---------------- butterfly: reduce o[8] over 64 lanes; lane<8 returns sum for d=((l&1)<<2)|(l&2)|((l>>2)&1) ----------------
__device__ __forceinline__ float bfly8(float o[8], int lane){
    int b0 = lane & 1, b1 = lane & 2, b2 = lane & 4;
    float n[4];
    #pragma unroll
    for (int j=0;j<4;j++){
        float give = b0 ? o[j] : o[j+4];
        float keep = b0 ? o[j+4] : o[j];
        n[j] = keep + __shfl_xor(give, 1);
    }
    float m2[2];
    #pragma unroll
    for (int j=0;j<2;j++){
        float give = b1 ? n[j] : n[j+2];
        float keep = b1 ? n[j+2] : n[j];
        m2[j] = keep + __shfl_xor(give, 2);
    }
    float give = b2 ? m2[0] : m2[1];
    float keep = b2 ? m2[1] : m2[0];
    float v = keep + __shfl_xor(give, 4);
    v += __shfl_xor(v, 8);
    v += __shfl_xor(v, 16);
    v += __shfl_xor(v, 32);
    return v;
}

// ---------------- attention: Q/K/V pre-computed; stage = pure loads; K/V hoisted to regs ----------------
__global__ __launch_bounds__(256)
void k_attn(const float* __restrict__ qkv, float* __restrict__ attn, float* __restrict__ obuf)
{
    int blk = blockIdx.x;
    int chunk = blk & 1;
    int bh = blk >> 1;
    int b = bh >> 2, h = bh & 3;
    __shared__ float4 KV[4][NP1];   // [kA(d0-3), kB(d4-7), vA, vB][row]
    __shared__ float4 QS[2][NP1];   // [qA, qB][row]
    int t = threadIdx.x;

    const float* qb = qkv + ((size_t)b*3 + 0)*NP1*32 + h*8;
    const float* kb = qkv + ((size_t)b*3 + 1)*NP1*32 + h*8;
    const float* vb = qkv + ((size_t)b*3 + 2)*NP1*32 + h*8;
    for (int i = t; i < NP1*6; i += 256){
        int r = i / 6, s = i - 6*(i/6);
        int dq = s & 1;
        if (s < 2)      QS[dq][r]   = *(const float4*)&qb[(size_t)r*32 + dq*4];
        else if (s < 4) KV[dq][r]   = *(const float4*)&kb[(size_t)r*32 + dq*4];
        else            KV[2+dq][r] = *(const float4*)&vb[(size_t)r*32 + dq*4];
    }
    __syncthreads();

    int w = t >> 6, lane = t & 63;
    float kreg[6][8], vreg[6][8];
    #pragma unroll
    for (int j=0;j<6;j++){
        int ki = lane + (j<<6);
        int kc = ki > 360 ? 360 : ki;
        float4 ka = KV[0][kc], kb2 = KV[1][kc];
        float4 va = KV[2][kc], vb2 = KV[3][kc];
        kreg[j][0]=ka.x; kreg[j][1]=ka.y; kreg[j][2]=ka.z; kreg[j][3]=ka.w;
        kreg[j][4]=kb2.x; kreg[j][5]=kb2.y; kreg[j][6]=kb2.z; kreg[j][7]=kb2.w;
        vreg[j][0]=va.x; vreg[j][1]=va.y; vreg[j][2]=va.z; vreg[j][3]=va.w;
        vreg[j][4]=vb2.x; vreg[j][5]=vb2.y; vreg[j][6]=vb2.z; vreg[j][7]=vb2.w;
    }

    int cbase = chunk * 181;
    int cend  = chunk ? NP1 : 181;

    for (int qi0 = cbase + (w<<1); qi0 < cend; qi0 += 8){
        int qi1 = qi0 + 1;
        bool v1 = (qi1 < cend);

        float q0[8], q1[8];
        {
            float4 a = QS[0][qi0], c = QS[1][qi0];
            q0[0]=a.x;q0[1]=a.y;q0[2]=a.z;q0[3]=a.w;q0[4]=c.x;q0[5]=c.y;q0[6]=c.z;q0[7]=c.w;
            float4 a1 = QS[0][qi1], c1 = QS[1][qi1];   // qi1 <= 360 always (store-guarded)
            q1[0]=a1.x;q1[1]=a1.y;q1[2]=a1.z;q1[3]=a1.w;q1[4]=c1.x;q1[5]=c1.y;q1[6]=c1.z;q1[7]=c1.w;
        }

        float e0[6], e1[6];
        float mx0 = -1e30f, mx1 = -1e30f;
        #pragma unroll
        for (int j=0;j<6;j++){
            int ki = lane + (j<<6);
            float s0 = 0.f, s1 = 0.f;
            #pragma unroll
            for (int d=0;d<8;d++){ s0 += q0[d]*kreg[j][d]; s1 += q1[d]*kreg[j][d]; }
            if (ki >= NP1){ s0 = -1e30f; s1 = -1e30f; }
            e0[j] = s0; e1[j] = s1;
            mx0 = fmaxf(mx0, s0); mx1 = fmaxf(mx1, s1);
        }
        #pragma unroll
        for (int off=32; off; off>>=1){
            mx0 = fmaxf(mx0, __shfl_xor(mx0, off));
            mx1 = fmaxf(mx1, __shfl_xor(mx1, off));
        }
        float sum0 = 0.f, sum1 = 0.f;
        #pragma unroll
        for (int j=0;j<6;j++){
            float p0 = __expf(e0[j]-mx0);
            float p1 = __expf(e1[j]-mx1);
            e0[j]=p0; e1[j]=p1;
            sum0 += p0; sum1 += p1;
        }
        #pragma unroll
        for (int off=32; off; off>>=1){
            sum0 += __shfl_xor(sum0, off);
            sum1 += __shfl_xor(sum1, off);
        }
        float inv0 = 1.f/sum0;
        float inv1 = 1.f/sum1;

        size_t abase = (size_t)bh*NP1*NP1 + (size_t)qi0*NP1;
        float o0[8] = {0,0,0,0,0,0,0,0};
        float o1[8] = {0,0,0,0,0,0,0,0};
        #pragma unroll
        for (int j=0;j<6;j++){
            int ki = lane + (j<<6);
            float p0 = e0[j]*inv0;
            float p1 = e1[j]*inv1;
            if (ki < NP1){
                attn[abase + ki] = p0;
                if (v1) attn[abase + NP1 + ki] = p1;
            }
            #pragma unroll
            for (int d=0;d<8;d++){
                o0[d] += p0*vreg[j][d];
                o1[d] += p1*vreg[j][d];
            }
        }
        float val0 = bfly8(o0, lane);
        float val1 = bfly8(o1, lane);
        int l7 = lane & 7;
        int dmap = ((l7&1)<<2) | (l7&2) | ((l7>>2)&1);
        if (lane < 8)
            obuf[((size_t)b*NP1 + qi0)*32 + h*8 + dmap] = val0;
        else if (lane < 16 && v1)
            obuf[((size_t)b*NP1 + qi1)*32 + h*8 + dmap] = val1;
    }
}

// ---------------- score + sigmoid + top-k select + softmax pool + MLP head ----------------
__global__ __launch_bounds__(256)
void k_pool(const float* __restrict__ attn, const float* __restrict__ obuf,
            const float* __restrict__ wo, const float* __restrict__ bo,
            const float* __restrict__ f1w, const float* __restrict__ f1b,
            const float* __restrict__ f2w, const float* __restrict__ f2b,
            const float* __restrict__ f3w, const float* __restrict__ f3b,
            float* __restrict__ out_sig, float* __restrict__ logits)
{
    int b = blockIdx.x;
    __shared__ float sc[NN];
    __shared__ float w[NN];
    __shared__ float red[256];
    __shared__ float pooled32[32];
    __shared__ float p16[16];
    __shared__ float h64[64];
    __shared__ float h32[32];
    int t = threadIdx.x;
    for (int i=t; i<NN; i+=256){
        float s = 0.f;
        #pragma unroll
        for (int h=0; h<4; h++)
            s += attn[(((size_t)b*4+h)*NP1)*NP1 + 1 + i];
        sc[i] = s;
        out_sig[b*NN + i] = 1.f/(1.f + __expf(-s));
    }
    __syncthreads();
    float mx = -1e30f;
    for (int i=t; i<NN; i+=256) mx = fmaxf(mx, sc[i]);
    red[t] = mx; __syncthreads();
    for (int s=128; s; s>>=1){ if (t<s) red[t]=fmaxf(red[t],red[t+s]); __syncthreads(); }
    mx = red[0];
    __syncthreads();
    float psum = 0.f;
    for (int i=t; i<NN; i+=256){
        float si = sc[i];
        int r = 0;
        for (int j=0;j<NN;j++){
            float sj = sc[j];
            r += (sj > si) || (sj == si && j < i);
        }
        float wi = (r < POOLL) ? __expf(si - mx) : 0.f;
        w[i] = wi;
        psum += wi;
    }
    red[t] = psum; __syncthreads();
    for (int s=128; s; s>>=1){ if (t<s) red[t]+=red[t+s]; __syncthreads(); }
    float inv = 1.f / red[0];
    __syncthreads();
    if (t < 32){
        float s = 0.f;
        for (int i=0;i<NN;i++) s += w[i] * obuf[((size_t)b*NP1 + 1 + i)*32 + t];
        pooled32[t] = s * inv;
    }
    __syncthreads();
    if (t < 16){
        float s = bo[t];
        for (int d=0;d<32;d++) s += pooled32[d]*wo[d*16+t];
        p16[t] = s;
    }
    __syncthreads();
    if (t < 64){
        float s = f1b[t];
        for (int c=0;c<16;c++) s += p16[c]*f1w[c*64+t];
        h64[t] = lrelu(s);
    }
    __syncthreads();
    if (t < 32){
        float s = f2b[t];
        for (int c=0;c<64;c++) s += h64[c]*f2w[c*32+t];
        h32[t] = lrelu(s);
    }
    __syncthreads();
    if (t < 2){
        float s = f3b[t];
        for (int c=0;c<32;c++) s += h32[c]*f3w[c*2+t];
        logits[b*2+t] = s;
    }
}

extern "C" void kernel_launch(void* const* d_in, const int* in_sizes, int n_in,
                              void* d_out, int out_size, void* d_ws, size_t ws_size,
                              hipStream_t stream)
{
    const float* m    = (const float*)d_in[0];
    const float* nf   = (const float*)d_in[1];
    const float* cls  = (const float*)d_in[2];
    const float* g0w  = (const float*)d_in[3];
    const float* g0b  = (const float*)d_in[4];
    const float* g1w  = (const float*)d_in[5];
    const float* g1b  = (const float*)d_in[6];
    const float* g2w1 = (const float*)d_in[7];
    const float* g2b1 = (const float*)d_in[8];
    const float* g2w2 = (const float*)d_in[9];
    const float* g2b2 = (const float*)d_in[10];
    const float* scw  = (const float*)d_in[11];
    const float* scb  = (const float*)d_in[12];
    const float* bn0g = (const float*)d_in[13];
    const float* bn0b = (const float*)d_in[14];
    const float* bn1g = (const float*)d_in[15];
    const float* bn1b = (const float*)d_in[16];
    const float* bn2g = (const float*)d_in[17];
    const float* bn2b = (const float*)d_in[18];
    const float* wq = (const float*)d_in[19];
    const float* bq = (const float*)d_in[20];
    const float* wk = (const float*)d_in[21];
    const float* bk = (const float*)d_in[22];
    const float* wv = (const float*)d_in[23];
    const float* bv = (const float*)d_in[24];
    const float* wo = (const float*)d_in[25];
    const float* bo = (const float*)d_in[26];
    const float* f1w = (const float*)d_in[27];
    const float* f1b = (const float*)d_in[28];
    const float* f2w = (const float*)d_in[29];
    const float* f2b = (const float*)d_in[30];
    const float* f3w = (const float*)d_in[31];
    const float* f3b = (const float*)d_in[32];

    float* out_logits = (float*)d_out;
    float* out_sig = out_logits + 512;
    float* attn = out_sig + (size_t)BZ*NN;

    // big scratch inside the attn output region (dead until k_attn writes it)
    char* base = (char*)attn;
    const size_t szy = (size_t)MROWS * KP * 2;            // bf16 plane
    ushort* y0h = (ushort*)base;
    ushort* y0l = (ushort*)(base + szy);
    ushort* y1h = (ushort*)(base + 2*szy);
    ushort* y1l = (ushort*)(base + 3*szy);
    float*  h1buf = (float*)(base + 4*szy);
    const size_t szh = (size_t)MROWS * 64 * 4;
    float*  scbuf = (float*)(base + 4*szy + szh);
    const size_t szsc = (size_t)MROWS * 16 * 4;
    ushort* Wt0h = (ushort*)(base + 4*szy + szh + szsc);
    ushort* Wt0l = Wt0h + (size_t)KP*KP;
    ushort* Wt1h = Wt0l + (size_t)KP*KP;
    ushort* Wt1l = Wt1h + (size_t)KP*KP;
    ushort* Wt2h = Wt1l + (size_t)KP*KP;
    ushort* Wt2l = Wt2h + (size_t)KP*KP;
    float*  c0  = (float*)(Wt2l + (size_t)KP*KP);
    float*  c1  = c0 + KP;
    float*  c2  = c1 + KP;

    float* ws = (float*)d_ws;
    float* rowsum = ws;                ws += MROWS;
    float* stats  = ws;                ws += 1472;
    float* cs0 = stats, *cq0 = stats+360, *cs1 = stats+720, *cq1 = stats+1080,
         * cs2 = stats+1440, *cq2 = stats+1456;
    float* s0 = ws;  ws += 360;
    float* h0 = ws;  ws += 360;
    float* s1 = ws;  ws += 360;
    float* hh1 = ws; ws += 360;
    float* s2 = ws;  ws += 16;
    float* h2 = ws;  ws += 16;
    float* x2 = ws;       ws += (size_t)MROWS*16;
    float* obuf = ws;     ws += (size_t)BZ*NP1*32;
    float* qkv = ws;      ws += (size_t)BZ*3*NP1*32;

    k_rowsum<<<MROWS/4, 256, 0, stream>>>(m, rowsum, stats);
    k_prepw<<<KP, KP, 0, stream>>>(g0w, 360, 0, nullptr, nullptr, Wt0h, Wt0l, c0);

    k_gemm_mfma<true,false><<<2160, 256, 0, stream>>>(nf, nullptr, Wt0h, Wt0l, c0, g0b, rowsum, nullptr, nullptr, y0h, y0l, cs0, cq0);
    k_bnfin<<<1, 384, 0, stream>>>(cs0, cq0, bn0g, bn0b, 360, s0, h0);
    k_prepw<<<KP, KP, 0, stream>>>(g1w, 360, 0, s0, h0, Wt1h, Wt1l, c1);
    k_gemm_mfma<false,true><<<2160, 256, 0, stream>>>(y0h, y0l, Wt1h, Wt1l, c1, g1b, rowsum, s0, h0, y1h, y1l, cs1, cq1);
    k_bnfin<<<1, 384, 0, stream>>>(cs1, cq1, bn1g, bn1b, 360, s1, hh1);
    k_prepw<<<64, KP, 0, stream>>>(g2w1, 64, 0, s1, hh1, Wt2h, Wt2l, c2);
    k_prepw<<<16, KP, 0, stream>>>(scw, 16, 64, s1, hh1, Wt2h, Wt2l, c2);
    k_gemm2_mfma<<<720, 256, 0, stream>>>(y1h, y1l, Wt2h, Wt2l, c2, g2b1, scb, rowsum, h1buf, scbuf);
    k_stage2<<<1440, 256, 0, stream>>>(h1buf, scbuf, g2w2, g2b2, x2, cs2, cq2);
    k_bnfin<<<1, 64, 0, stream>>>(cs2, cq2, bn2g, bn2b, 16, s2, h2);
    k_qkv<<<BZ, 256, 0, stream>>>(x2, s2, h2, cls, wq, bq, wk, bk, wv, bv, qkv);
    k_attn<<<BZ*4*2, 256, 0, stream>>>(qkv, attn, obuf);
    k_pool<<<BZ, 256, 0, stream>>>(attn, obuf, wo, bo, f1w, f1b, f2w, f2b, f3w, f3b, out_sig, out_logits);
}

// Round 12
// 733.758 us; speedup vs baseline: 1.0799x; 1.0112x over previous
//
#include <hip/hip_runtime.h>
#include <math.h>

#define BZ 256
#define NN 360
#define NP1 361
#define MROWS (BZ*NN)   // 92160
#define POOLL 252
#define KP 384          // padded K (12 tiles of 32)

typedef __attribute__((ext_vector_type(8))) short bf16x8;
typedef __attribute__((ext_vector_type(4))) float f32x4;

__device__ __forceinline__ float lrelu(float x){ return x > 0.f ? x : 0.2f*x; }

__device__ __forceinline__ ushort f2bf(float f){
    union { float f; uint u; } v; v.f = f;
    uint u = v.u + 0x7FFFu + ((v.u >> 16) & 1u);
    return (ushort)(u >> 16);
}
__device__ __forceinline__ float bf2f(ushort h){
    union { uint u; float f; } v; v.u = ((uint)h) << 16;
    return v.f;
}
__device__ __forceinline__ void split2(float v, ushort& hi, ushort& lo){
    hi = f2bf(v);
    lo = f2bf(v - bf2f(hi));
}

// async global->LDS, 16B per lane, dest = wave-uniform base + lane*16
__device__ __forceinline__ void gload16(const void* g, void* l){
    __builtin_amdgcn_global_load_lds((const __attribute__((address_space(1))) uint*)g,
                                     (__attribute__((address_space(3))) uint*)l, 16, 0, 0);
}

// stage one bf16 plane [128 rows x 32 cols] from src (row stride KP) into P with chunk swizzle
__device__ __forceinline__ void stage_plane(const ushort* __restrict__ src, size_t srow0,
                                            ushort (*P)[32], int k0, int t){
    int w = t >> 6;
    #pragma unroll
    for (int i=0;i<2;i++){
        int u = i*256 + t;
        int row = u >> 2, ccs = u & 3;
        int cg = ccs ^ ((row >> 1) & 3);
        const ushort* g = src + (srow0 + row)*KP + k0 + cg*8;
        char* l = (char*)P + i*4096 + w*1024;
        gload16(g, l);
    }
}

// fragment read from swizzled plane: logical (row, chunk g)
__device__ __forceinline__ bf16x8 frag_read(const ushort (*P)[32], int row, int g){
    return *(const bf16x8*)((const char*)P + row*64 + ((g ^ ((row >> 1) & 3)) * 16));
}

// ---------------- rowsum (+ stats zero): one wave per row, float4 ----------------
__global__ __launch_bounds__(256)
void k_rowsum(const float* __restrict__ m, float* __restrict__ rowsum, float* __restrict__ stats){
    int gi = blockIdx.x*blockDim.x + threadIdx.x;
    if (gi < 1472) stats[gi] = 0.f;
    int wid = gi >> 6;
    int lane = threadIdx.x & 63;
    if (wid >= MROWS) return;
    const float4* p = (const float4*)(m + (size_t)wid*NN);
    float s = 0.f;
    {
        float4 f = p[lane];
        s += f.x + f.y + f.z + f.w;
    }
    if (lane < 26){
        float4 f = p[64 + lane];
        s += f.x + f.y + f.z + f.w;
    }
    #pragma unroll
    for (int off = 32; off; off >>= 1) s += __shfl_down(s, off);
    if (lane == 0) rowsum[wid] = s;
}

// ---------------- weight prep ----------------
__global__ __launch_bounds__(384)
void k_prepw(const float* __restrict__ W, int ncols, int joff,
             const float* __restrict__ s, const float* __restrict__ h,
             ushort* __restrict__ Wth, ushort* __restrict__ Wtl, float* __restrict__ cvec)
{
    int j = blockIdx.x;
    int k = threadIdx.x;      // 0..383
    __shared__ float red[6];
    float wv = 0.f, hv = 0.f, sv = 1.f;
    if (k < NN && j < ncols){
        wv = W[(size_t)k*ncols + j];
        if (s) sv = s[k];
        if (h) hv = h[k];
    }
    ushort hi, lo; split2(wv * sv, hi, lo);
    Wth[(size_t)(joff + j)*KP + k] = hi;
    Wtl[(size_t)(joff + j)*KP + k] = lo;
    float v = hv * wv;
    #pragma unroll
    for (int off = 32; off; off >>= 1) v += __shfl_down(v, off);
    int lane = k & 63, wid = k >> 6;
    if (lane == 0) red[wid] = v;
    __syncthreads();
    if (k == 0) cvec[joff + j] = red[0]+red[1]+red[2]+red[3]+red[4]+red[5];
}

// ---------------- big MFMA GEMM, split-bf16 (3-term), 128x128 tile, global_load_lds staging ----------------
template<bool AF32, bool RESID>
__global__ __launch_bounds__(256)
void k_gemm_mfma(const void* __restrict__ Avh, const ushort* __restrict__ Avl,
                 const ushort* __restrict__ Wth, const ushort* __restrict__ Wtl,
                 const float* __restrict__ cvec, const float* __restrict__ bias,
                 const float* __restrict__ rowsum,
                 const float* __restrict__ bns, const float* __restrict__ bnh,
                 ushort* __restrict__ Yhi, ushort* __restrict__ Ylo,
                 float* __restrict__ colsum, float* __restrict__ colsq)
{
    __shared__ ushort Ah[128][32];
    __shared__ ushort Al[128][32];
    __shared__ ushort Bh[128][32];
    __shared__ ushort Bl[128][32];
    int t = threadIdx.x;
    int w = t >> 6, lane = t & 63;
    int l15 = lane & 15, g = lane >> 4;
    int idx = blockIdx.x;
    int gr = idx & 7;
    int rem = idx >> 3;
    int jcb = rem % 3;
    int gq = rem / 3;
    int rowblk = (gq*8 + gr) * 128;
    int colblk = jcb * 128;

    f32x4 acc[2][8];
    #pragma unroll
    for (int i=0;i<2;i++)
        #pragma unroll
        for (int j=0;j<8;j++)
            #pragma unroll
            for (int e=0;e<4;e++) acc[i][j][e] = 0.f;

    for (int kt = 0; kt < 12; ++kt){
        int k0 = kt * 32;
        if (AF32){
            const float* A = (const float*)Avh;
            int row = t >> 1, half = t & 1;
            int fr = (row >> 1) & 3;
            #pragma unroll
            for (int c=0;c<2;c++){
                int cg = half*2 + c;
                int k = k0 + cg*8;
                float4 f0 = make_float4(0.f,0.f,0.f,0.f);
                float4 f1 = make_float4(0.f,0.f,0.f,0.f);
                if (k < NN){
                    f0 = *(const float4*)&A[(size_t)(rowblk+row)*NN + k];
                    f1 = *(const float4*)&A[(size_t)(rowblk+row)*NN + k + 4];
                }
                ushort h0,l0,h1,l1,h2,l2,h3,l3,h4,l4,h5,l5,h6,l6,h7,l7;
                split2(f0.x,h0,l0); split2(f0.y,h1,l1); split2(f0.z,h2,l2); split2(f0.w,h3,l3);
                split2(f1.x,h4,l4); split2(f1.y,h5,l5); split2(f1.z,h6,l6); split2(f1.w,h7,l7);
                uint4 hv = make_uint4((uint)h0|((uint)h1<<16), (uint)h2|((uint)h3<<16),
                                      (uint)h4|((uint)h5<<16), (uint)h6|((uint)h7<<16));
                uint4 lv = make_uint4((uint)l0|((uint)l1<<16), (uint)l2|((uint)l3<<16),
                                      (uint)l4|((uint)l5<<16), (uint)l6|((uint)l7<<16));
                int ccs = cg ^ fr;
                *(uint4*)((char*)Ah + row*64 + ccs*16) = hv;
                *(uint4*)((char*)Al + row*64 + ccs*16) = lv;
            }
        } else {
            stage_plane((const ushort*)Avh, (size_t)rowblk, Ah, k0, t);
            stage_plane(Avl,               (size_t)rowblk, Al, k0, t);
        }
        stage_plane(Wth, (size_t)colblk, Bh, k0, t);
        stage_plane(Wtl, (size_t)colblk, Bl, k0, t);
        __syncthreads();

        bf16x8 ah0 = frag_read(Ah, 32*w + l15, g);
        bf16x8 ah1 = frag_read(Ah, 32*w + 16 + l15, g);
        bf16x8 al0 = frag_read(Al, 32*w + l15, g);
        bf16x8 al1 = frag_read(Al, 32*w + 16 + l15, g);
        #pragma unroll
        for (int nj=0;nj<8;nj++){
            bf16x8 bh = frag_read(Bh, 16*nj + l15, g);
            bf16x8 bl = frag_read(Bl, 16*nj + l15, g);
            acc[0][nj] = __builtin_amdgcn_mfma_f32_16x16x32_bf16(ah0, bh, acc[0][nj], 0, 0, 0);
            acc[0][nj] = __builtin_amdgcn_mfma_f32_16x16x32_bf16(al0, bh, acc[0][nj], 0, 0, 0);
            acc[0][nj] = __builtin_amdgcn_mfma_f32_16x16x32_bf16(ah0, bl, acc[0][nj], 0, 0, 0);
            acc[1][nj] = __builtin_amdgcn_mfma_f32_16x16x32_bf16(ah1, bh, acc[1][nj], 0, 0, 0);
            acc[1][nj] = __builtin_amdgcn_mfma_f32_16x16x32_bf16(al1, bh, acc[1][nj], 0, 0, 0);
            acc[1][nj] = __builtin_amdgcn_mfma_f32_16x16x32_bf16(ah1, bl, acc[1][nj], 0, 0, 0);
        }
        __syncthreads();
    }

    const ushort* AHg = (const ushort*)Avh;
    float cs_part[8] = {0,0,0,0,0,0,0,0}, cq_part[8] = {0,0,0,0,0,0,0,0};
    #pragma unroll
    for (int mi=0;mi<2;mi++){
        #pragma unroll
        for (int nj=0;nj<8;nj++){
            f32x4 d = acc[mi][nj];
            #pragma unroll
            for (int r=0;r<4;r++){
                int row = rowblk + 32*w + 16*mi + 4*g + r;
                int col = colblk + 16*nj + l15;
                float v = 0.f;
                if (col < NN){
                    float pre = rowsum[row] * (d[r] + cvec[col]) + bias[col];
                    v = lrelu(pre);
                    if (RESID){
                        size_t ai = (size_t)row*KP + col;
                        float ar = bf2f(AHg[ai]) + bf2f(Avl[ai]);
                        v += ar * bns[col] + bnh[col];
                    }
                }
                ushort hi, lo; split2(v, hi, lo);
                Yhi[(size_t)row*KP + col] = hi;
                Ylo[(size_t)row*KP + col] = lo;
                cs_part[nj] += v;
                cq_part[nj] += v*v;
            }
        }
    }
    #pragma unroll
    for (int nj=0;nj<8;nj++){
        cs_part[nj] += __shfl_xor(cs_part[nj], 16); cs_part[nj] += __shfl_xor(cs_part[nj], 32);
        cq_part[nj] += __shfl_xor(cq_part[nj], 16); cq_part[nj] += __shfl_xor(cq_part[nj], 32);
    }
    float* red = (float*)&Ah[0][0];      // 512 floats used
    if (lane < 16){
        #pragma unroll
        for (int nj=0;nj<8;nj++) red[w*128 + nj*16 + l15] = cs_part[nj];
    }
    __syncthreads();
    if (t < 128 && colblk + t < NN)
        atomicAdd(&colsum[colblk + t], red[t] + red[128+t] + red[256+t] + red[384+t]);
    __syncthreads();
    if (lane < 16){
        #pragma unroll
        for (int nj=0;nj<8;nj++) red[w*128 + nj*16 + l15] = cq_part[nj];
    }
    __syncthreads();
    if (t < 128 && colblk + t < NN)
        atomicAdd(&colsq[colblk + t], red[t] + red[128+t] + red[256+t] + red[384+t]);
}

// ---------------- BN finalize ----------------
__global__ void k_bnfin(const float* __restrict__ colsum, const float* __restrict__ colsq,
                        const float* __restrict__ g, const float* __restrict__ b, int ncols,
                        float* __restrict__ scale, float* __restrict__ shift){
    int j = blockIdx.x*blockDim.x + threadIdx.x;
    if (j >= ncols) return;
    float mu = colsum[j] / (float)MROWS;
    float var = colsq[j] / (float)MROWS - mu*mu;
    float sc = g[j] * rsqrtf(var + 1e-5f);
    scale[j] = sc;
    shift[j] = b[j] - mu*sc;
}

// ---------------- gemm2: A via global_load_lds (swizzled), B reg-staged padded ----------------
__global__ __launch_bounds__(256)
void k_gemm2_mfma(const ushort* __restrict__ AH, const ushort* __restrict__ AL,
                  const ushort* __restrict__ Wth, const ushort* __restrict__ Wtl,
                  const float* __restrict__ cvec, const float* __restrict__ b1,
                  const float* __restrict__ scb, const float* __restrict__ rowsum,
                  float* __restrict__ h1buf, float* __restrict__ scbuf)
{
    __shared__ ushort Ah[128][32];
    __shared__ ushort Al[128][32];
    __shared__ ushort Bh[80][40];
    __shared__ ushort Bl[80][40];
    int t = threadIdx.x;
    int w = t >> 6, lane = t & 63;
    int l15 = lane & 15, g = lane >> 4;
    int rowblk = blockIdx.x * 128;

    f32x4 acc[2][5];
    #pragma unroll
    for (int i=0;i<2;i++)
        #pragma unroll
        for (int j=0;j<5;j++)
            #pragma unroll
            for (int e=0;e<4;e++) acc[i][j][e] = 0.f;

    for (int kt = 0; kt < 12; ++kt){
        int k0 = kt * 32;
        stage_plane(AH, (size_t)rowblk, Ah, k0, t);
        stage_plane(AL, (size_t)rowblk, Al, k0, t);
        #pragma unroll
        for (int l=0;l<2;l++){
            int c = t + l*256;
            if (c < 320){
                int col = c >> 2, kk = (c & 3)*8;
                ((int4*)&Bh[col][kk])[0] = *(const int4*)&Wth[(size_t)col*KP + k0 + kk];
                ((int4*)&Bl[col][kk])[0] = *(const int4*)&Wtl[(size_t)col*KP + k0 + kk];
            }
        }
        __syncthreads();
        bf16x8 ah0 = frag_read(Ah, 32*w + l15, g);
        bf16x8 ah1 = frag_read(Ah, 32*w + 16 + l15, g);
        bf16x8 al0 = frag_read(Al, 32*w + l15, g);
        bf16x8 al1 = frag_read(Al, 32*w + 16 + l15, g);
        #pragma unroll
        for (int nj=0;nj<5;nj++){
            bf16x8 bh = *(const bf16x8*)&Bh[16*nj + l15][8*g];
            bf16x8 bl = *(const bf16x8*)&Bl[16*nj + l15][8*g];
            acc[0][nj] = __builtin_amdgcn_mfma_f32_16x16x32_bf16(ah0, bh, acc[0][nj], 0, 0, 0);
            acc[0][nj] = __builtin_amdgcn_mfma_f32_16x16x32_bf16(al0, bh, acc[0][nj], 0, 0, 0);
            acc[0][nj] = __builtin_amdgcn_mfma_f32_16x16x32_bf16(ah0, bl, acc[0][nj], 0, 0, 0);
            acc[1][nj] = __builtin_amdgcn_mfma_f32_16x16x32_bf16(ah1, bh, acc[1][nj], 0, 0, 0);
            acc[1][nj] = __builtin_amdgcn_mfma_f32_16x16x32_bf16(al1, bh, acc[1][nj], 0, 0, 0);
            acc[1][nj] = __builtin_amdgcn_mfma_f32_16x16x32_bf16(ah1, bl, acc[1][nj], 0, 0, 0);
        }
        __syncthreads();
    }

    #pragma unroll
    for (int mi=0;mi<2;mi++){
        #pragma unroll
        for (int nj=0;nj<5;nj++){
            f32x4 d = acc[mi][nj];
            #pragma unroll
            for (int r=0;r<4;r++){
                int row = rowblk + 32*w + 16*mi + 4*g + r;
                int col = 16*nj + l15;
                if (nj < 4){
                    float pre = rowsum[row] * (d[r] + cvec[col]) + b1[col];
                    h1buf[(size_t)row*64 + col] = lrelu(pre);
                } else {
                    int cc = col - 64;
                    float pre = d[r] + cvec[col] + scb[cc];
                    scbuf[(size_t)row*16 + cc] = lrelu(pre);
                }
            }
        }
    }
}

// ---------------- stage2 ----------------
__global__ __launch_bounds__(256)
void k_stage2(const float* __restrict__ h1buf, const float* __restrict__ scbuf,
              const float* __restrict__ w2, const float* __restrict__ b2,
              float* __restrict__ x2, float* __restrict__ colsum, float* __restrict__ colsq)
{
    __shared__ float Hs[64][65];
    __shared__ float Ws[64][17];
    __shared__ float red[16][16];
    int t = threadIdx.x;
    int rowblk = blockIdx.x * 64;
    #pragma unroll
    for (int l=0;l<4;l++){
        int idx = t + l*256;
        Ws[idx>>4][idx&15] = w2[idx];
    }
    #pragma unroll
    for (int l=0;l<16;l++){
        int idx = t + l*256;
        Hs[idx>>6][idx&63] = h1buf[(size_t)rowblk*64 + idx];
    }
    __syncthreads();
    int col = t & 15, rb = t >> 4;
    float ps=0.f, pq=0.f;
    #pragma unroll
    for (int gg=0; gg<4; gg++){
        int r = rb + gg*16;
        float s = b2[col];
        #pragma unroll
        for (int c=0;c<64;c++) s += Hs[r][c]*Ws[c][col];
        float v = lrelu(s) + scbuf[(size_t)(rowblk+r)*16 + col];
        x2[(size_t)(rowblk+r)*16 + col] = v;
        ps += v; pq += v*v;
    }
    red[rb][col] = ps; __syncthreads();
    if (t < 16){
        float s=0.f;
        for (int g=0; g<16; g++) s += red[g][t];
        atomicAdd(&colsum[t], s);
    }
    __syncthreads();
    red[rb][col] = pq; __syncthreads();
    if (t < 16){
        float s=0.f;
        for (int g=0; g<16; g++) s += red[g][t];
        atomicAdd(&colsq[t], s);
    }
}

// ---------------- QKV precompute: qkv[b][tensor][r][32] (q pre-scaled, biases folded) ----------------
__global__ __launch_bounds__(256)
void k_qkv(const float* __restrict__ x2, const float* __restrict__ s2, const float* __restrict__ h2,
           const float* __restrict__ cls,
           const float* __restrict__ wq, const float* __restrict__ bq,
           const float* __restrict__ wk, const float* __restrict__ bk,
           const float* __restrict__ wv, const float* __restrict__ bv,
           float* __restrict__ qkv)
{
    int b = blockIdx.x;
    __shared__ float4 xin[NP1][4];
    int t = threadIdx.x;
    for (int i = t; i < NP1*4; i += 256){
        int r = i >> 2, c4 = i & 3;
        float4 f;
        if (r == 0) f = ((const float4*)cls)[c4];
        else {
            f = *(const float4*)&x2[((size_t)b*NN + r-1)*16 + c4*4];
            f.x = f.x*s2[c4*4+0] + h2[c4*4+0];
            f.y = f.y*s2[c4*4+1] + h2[c4*4+1];
            f.z = f.z*s2[c4*4+2] + h2[c4*4+2];
            f.w = f.w*s2[c4*4+3] + h2[c4*4+3];
        }
        xin[r][c4] = f;
    }
    __syncthreads();
    for (int task = t; task < 3*NP1*8; task += 256){
        int tn = task / (NP1*8);
        int rem = task - tn*(NP1*8);
        int r = rem >> 3, d4 = rem & 7;
        const float* W  = (tn==0) ? wq : ((tn==1) ? wk : wv);
        const float* Bb = (tn==0) ? bq : ((tn==1) ? bk : bv);
        float o0 = Bb[d4*4+0], o1 = Bb[d4*4+1], o2 = Bb[d4*4+2], o3 = Bb[d4*4+3];
        #pragma unroll
        for (int c4=0;c4<4;c4++){
            float4 xf = xin[r][c4];
            float xs[4] = {xf.x, xf.y, xf.z, xf.w};
            #pragma unroll
            for (int cc=0;cc<4;cc++){
                int c = c4*4 + cc;
                float x = xs[cc];
                o0 += x * W[c*32 + d4*4 + 0];
                o1 += x * W[c*32 + d4*4 + 1];
                o2 += x * W[c*32 + d4*4 + 2];
                o3 += x * W[c*32 + d4*4 + 3];
            }
        }
        if (tn == 0){
            const float sc = 0.35355339059327373f;
            o0 *= sc; o1 *= sc; o2 *= sc; o3 *= sc;
        }
        *(float4*)&qkv[(((size_t)b*3 + tn)*NP1 + r)*32 + d4*4] = make_float4(o0,o1,o2,o3);
    }
}

// ---------------- butterfly: reduce o[8] over 64 lanes; lane<8 returns sum for d=((l&1)<<2)|(l&2)|((l>>2)&1) ----------------
__device__ __forceinline__ float bfly8(float o[8], int lane){
    int b0 = lane & 1, b1 = lane & 2, b2 = lane & 4;
    float n[4];
    #pragma unroll
    for (int j=0;j<4;j++){
        float give = b0 ? o[j] : o[j+4];
        float keep = b0 ? o[j+4] : o[j];
        n[j] = keep + __shfl_xor(give, 1);
    }
    float m2[2];
    #pragma unroll
    for (int j=0;j<2;j++){
        float give = b1 ? n[j] : n[j+2];
        float keep = b1 ? n[j+2] : n[j];
        m2[j] = keep + __shfl_xor(give, 2);
    }
    float give = b2 ? m2[0] : m2[1];
    float keep = b2 ? m2[1] : m2[0];
    float v = keep + __shfl_xor(give, 4);
    v += __shfl_xor(v, 8);
    v += __shfl_xor(v, 16);
    v += __shfl_xor(v, 32);
    return v;
}

// ---------------- attention: QS holds only this chunk's q-rows (28.9 KB LDS -> 5 blocks/CU) ----------------
__global__ __launch_bounds__(256)
void k_attn(const float* __restrict__ qkv, float* __restrict__ attn, float* __restrict__ obuf)
{
    int blk = blockIdx.x;
    int chunk = blk & 1;
    int bh = blk >> 1;
    int b = bh >> 2, h = bh & 3;
    __shared__ float4 KV[4][NP1];   // [kA(d0-3), kB(d4-7), vA, vB][row]
    __shared__ float4 QS[2][181];   // [qA, qB][row - cbase], chunk rows only
    int t = threadIdx.x;

    int cbase = chunk * 181;
    int cend  = chunk ? NP1 : 181;
    int nrows = cend - cbase;       // 181 (chunk 0) or 180 (chunk 1)

    const float* qb = qkv + ((size_t)b*3 + 0)*NP1*32 + h*8;
    const float* kb = qkv + ((size_t)b*3 + 1)*NP1*32 + h*8;
    const float* vb = qkv + ((size_t)b*3 + 2)*NP1*32 + h*8;
    for (int i = t; i < NP1*4; i += 256){
        int r = i >> 2, s = i & 3;
        int dq = s & 1;
        const float* src = (s < 2) ? kb : vb;
        KV[(s < 2 ? 0 : 2) + dq][r] = *(const float4*)&src[(size_t)r*32 + dq*4];
    }
    for (int i = t; i < nrows*2; i += 256){
        int r = i >> 1, dq = i & 1;
        QS[dq][r] = *(const float4*)&qb[(size_t)(cbase + r)*32 + dq*4];
    }
    __syncthreads();

    int w = t >> 6, lane = t & 63;
    float kreg[6][8], vreg[6][8];
    #pragma unroll
    for (int j=0;j<6;j++){
        int ki = lane + (j<<6);
        int kc = ki > 360 ? 360 : ki;
        float4 ka = KV[0][kc], kb2 = KV[1][kc];
        float4 va = KV[2][kc], vb2 = KV[3][kc];
        kreg[j][0]=ka.x; kreg[j][1]=ka.y; kreg[j][2]=ka.z; kreg[j][3]=ka.w;
        kreg[j][4]=kb2.x; kreg[j][5]=kb2.y; kreg[j][6]=kb2.z; kreg[j][7]=kb2.w;
        vreg[j][0]=va.x; vreg[j][1]=va.y; vreg[j][2]=va.z; vreg[j][3]=va.w;
        vreg[j][4]=vb2.x; vreg[j][5]=vb2.y; vreg[j][6]=vb2.z; vreg[j][7]=vb2.w;
    }

    for (int qi0 = cbase + (w<<1); qi0 < cend; qi0 += 8){
        int qi1 = qi0 + 1;
        bool v1 = (qi1 < cend);
        int q0i = qi0 - cbase;
        int q1i = v1 ? (qi1 - cbase) : q0i;

        float q0[8], q1[8];
        {
            float4 a = QS[0][q0i], c = QS[1][q0i];
            q0[0]=a.x;q0[1]=a.y;q0[2]=a.z;q0[3]=a.w;q0[4]=c.x;q0[5]=c.y;q0[6]=c.z;q0[7]=c.w;
            float4 a1 = QS[0][q1i], c1 = QS[1][q1i];
            q1[0]=a1.x;q1[1]=a1.y;q1[2]=a1.z;q1[3]=a1.w;q1[4]=c1.x;q1[5]=c1.y;q1[6]=c1.z;q1[7]=c1.w;
        }

        float e0[6], e1[6];
        float mx0 = -1e30f, mx1 = -1e30f;
        #pragma unroll
        for (int j=0;j<6;j++){
            int ki = lane + (j<<6);
            float s0 = 0.f, s1 = 0.f;
            #pragma unroll
            for (int d=0;d<8;d++){ s0 += q0[d]*kreg[j][d]; s1 += q1[d]*kreg[j][d]; }
            if (ki >= NP1){ s0 = -1e30f; s1 = -1e30f; }
            e0[j] = s0; e1[j] = s1;
            mx0 = fmaxf(mx0, s0); mx1 = fmaxf(mx1, s1);
        }
        #pragma unroll
        for (int off=32; off; off>>=1){
            mx0 = fmaxf(mx0, __shfl_xor(mx0, off));
            mx1 = fmaxf(mx1, __shfl_xor(mx1, off));
        }
        float sum0 = 0.f, sum1 = 0.f;
        #pragma unroll
        for (int j=0;j<6;j++){
            float p0 = __expf(e0[j]-mx0);
            float p1 = __expf(e1[j]-mx1);
            e0[j]=p0; e1[j]=p1;
            sum0 += p0; sum1 += p1;
        }
        #pragma unroll
        for (int off=32; off; off>>=1){
            sum0 += __shfl_xor(sum0, off);
            sum1 += __shfl_xor(sum1, off);
        }
        float inv0 = 1.f/sum0;
        float inv1 = 1.f/sum1;

        size_t abase = (size_t)bh*NP1*NP1 + (size_t)qi0*NP1;
        float o0[8] = {0,0,0,0,0,0,0,0};
        float o1[8] = {0,0,0,0,0,0,0,0};
        #pragma unroll
        for (int j=0;j<6;j++){
            int ki = lane + (j<<6);
            float p0 = e0[j]*inv0;
            float p1 = e1[j]*inv1;
            if (ki < NP1){
                attn[abase + ki] = p0;
                if (v1) attn[abase + NP1 + ki] = p1;
            }
            #pragma unroll
            for (int d=0;d<8;d++){
                o0[d] += p0*vreg[j][d];
                o1[d] += p1*vreg[j][d];
            }
        }
        float val0 = bfly8(o0, lane);
        float val1 = bfly8(o1, lane);
        int l7 = lane & 7;
        int dmap = ((l7&1)<<2) | (l7&2) | ((l7>>2)&1);
        if (lane < 8)
            obuf[((size_t)b*NP1 + qi0)*32 + h*8 + dmap] = val0;
        else if (lane < 16 && v1)
            obuf[((size_t)b*NP1 + qi1)*32 + h*8 + dmap] = val1;
    }
}

// ---------------- score + sigmoid + top-k select + softmax pool + MLP head ----------------
__global__ __launch_bounds__(256)
void k_pool(const float* __restrict__ attn, const float* __restrict__ obuf,
            const float* __restrict__ wo, const float* __restrict__ bo,
            const float* __restrict__ f1w, const float* __restrict__ f1b,
            const float* __restrict__ f2w, const float* __restrict__ f2b,
            const float* __restrict__ f3w, const float* __restrict__ f3b,
            float* __restrict__ out_sig, float* __restrict__ logits)
{
    int b = blockIdx.x;
    __shared__ float sc[NN];
    __shared__ float w[NN];
    __shared__ float red[256];
    __shared__ float pooled32[32];
    __shared__ float p16[16];
    __shared__ float h64[64];
    __shared__ float h32[32];
    int t = threadIdx.x;
    for (int i=t; i<NN; i+=256){
        float s = 0.f;
        #pragma unroll
        for (int h=0; h<4; h++)
            s += attn[(((size_t)b*4+h)*NP1)*NP1 + 1 + i];
        sc[i] = s;
        out_sig[b*NN + i] = 1.f/(1.f + __expf(-s));
    }
    __syncthreads();
    float mx = -1e30f;
    for (int i=t; i<NN; i+=256) mx = fmaxf(mx, sc[i]);
    red[t] = mx; __syncthreads();
    for (int s=128; s; s>>=1){ if (t<s) red[t]=fmaxf(red[t],red[t+s]); __syncthreads(); }
    mx = red[0];
    __syncthreads();
    float psum = 0.f;
    for (int i=t; i<NN; i+=256){
        float si = sc[i];
        int r = 0;
        for (int j=0;j<NN;j++){
            float sj = sc[j];
            r += (sj > si) || (sj == si && j < i);
        }
        float wi = (r < POOLL) ? __expf(si - mx) : 0.f;
        w[i] = wi;
        psum += wi;
    }
    red[t] = psum; __syncthreads();
    for (int s=128; s; s>>=1){ if (t<s) red[t]+=red[t+s]; __syncthreads(); }
    float inv = 1.f / red[0];
    __syncthreads();
    if (t < 32){
        float s = 0.f;
        for (int i=0;i<NN;i++) s += w[i] * obuf[((size_t)b*NP1 + 1 + i)*32 + t];
        pooled32[t] = s * inv;
    }
    __syncthreads();
    if (t < 16){
        float s = bo[t];
        for (int d=0;d<32;d++) s += pooled32[d]*wo[d*16+t];
        p16[t] = s;
    }
    __syncthreads();
    if (t < 64){
        float s = f1b[t];
        for (int c=0;c<16;c++) s += p16[c]*f1w[c*64+t];
        h64[t] = lrelu(s);
    }
    __syncthreads();
    if (t < 32){
        float s = f2b[t];
        for (int c=0;c<64;c++) s += h64[c]*f2w[c*32+t];
        h32[t] = lrelu(s);
    }
    __syncthreads();
    if (t < 2){
        float s = f3b[t];
        for (int c=0;c<32;c++) s += h32[c]*f3w[c*2+t];
        logits[b*2+t] = s;
    }
}

extern "C" void kernel_launch(void* const* d_in, const int* in_sizes, int n_in,
                              void* d_out, int out_size, void* d_ws, size_t ws_size,
                              hipStream_t stream)
{
    const float* m    = (const float*)d_in[0];
    const float* nf   = (const float*)d_in[1];
    const float* cls  = (const float*)d_in[2];
    const float* g0w  = (const float*)d_in[3];
    const float* g0b  = (const float*)d_in[4];
    const float* g1w  = (const float*)d_in[5];
    const float* g1b  = (const float*)d_in[6];
    const float* g2w1 = (const float*)d_in[7];
    const float* g2b1 = (const float*)d_in[8];
    const float* g2w2 = (const float*)d_in[9];
    const float* g2b2 = (const float*)d_in[10];
    const float* scw  = (const float*)d_in[11];
    const float* scb  = (const float*)d_in[12];
    const float* bn0g = (const float*)d_in[13];
    const float* bn0b = (const float*)d_in[14];
    const float* bn1g = (const float*)d_in[15];
    const float* bn1b = (const float*)d_in[16];
    const float* bn2g = (const float*)d_in[17];
    const float* bn2b = (const float*)d_in[18];
    const float* wq = (const float*)d_in[19];
    const float* bq = (const float*)d_in[20];
    const float* wk = (const float*)d_in[21];
    const float* bk = (const float*)d_in[22];
    const float* wv = (const float*)d_in[23];
    const float* bv = (const float*)d_in[24];
    const float* wo = (const float*)d_in[25];
    const float* bo = (const float*)d_in[26];
    const float* f1w = (const float*)d_in[27];
    const float* f1b = (const float*)d_in[28];
    const float* f2w = (const float*)d_in[29];
    const float* f2b = (const float*)d_in[30];
    const float* f3w = (const float*)d_in[31];
    const float* f3b = (const float*)d_in[32];

    float* out_logits = (float*)d_out;
    float* out_sig = out_logits + 512;
    float* attn = out_sig + (size_t)BZ*NN;

    // big scratch inside the attn output region (dead until k_attn writes it)
    char* base = (char*)attn;
    const size_t szy = (size_t)MROWS * KP * 2;            // bf16 plane
    ushort* y0h = (ushort*)base;
    ushort* y0l = (ushort*)(base + szy);
    ushort* y1h = (ushort*)(base + 2*szy);
    ushort* y1l = (ushort*)(base + 3*szy);
    float*  h1buf = (float*)(base + 4*szy);
    const size_t szh = (size_t)MROWS * 64 * 4;
    float*  scbuf = (float*)(base + 4*szy + szh);
    const size_t szsc = (size_t)MROWS * 16 * 4;
    ushort* Wt0h = (ushort*)(base + 4*szy + szh + szsc);
    ushort* Wt0l = Wt0h + (size_t)KP*KP;
    ushort* Wt1h = Wt0l + (size_t)KP*KP;
    ushort* Wt1l = Wt1h + (size_t)KP*KP;
    ushort* Wt2h = Wt1l + (size_t)KP*KP;
    ushort* Wt2l = Wt2h + (size_t)KP*KP;
    float*  c0  = (float*)(Wt2l + (size_t)KP*KP);
    float*  c1  = c0 + KP;
    float*  c2  = c1 + KP;

    float* ws = (float*)d_ws;
    float* rowsum = ws;                ws += MROWS;
    float* stats  = ws;                ws += 1472;
    float* cs0 = stats, *cq0 = stats+360, *cs1 = stats+720, *cq1 = stats+1080,
         * cs2 = stats+1440, *cq2 = stats+1456;
    float* s0 = ws;  ws += 360;
    float* h0 = ws;  ws += 360;
    float* s1 = ws;  ws += 360;
    float* hh1 = ws; ws += 360;
    float* s2 = ws;  ws += 16;
    float* h2 = ws;  ws += 16;
    float* x2 = ws;       ws += (size_t)MROWS*16;
    float* obuf = ws;     ws += (size_t)BZ*NP1*32;
    float* qkv = ws;      ws += (size_t)BZ*3*NP1*32;

    k_rowsum<<<MROWS/4, 256, 0, stream>>>(m, rowsum, stats);
    k_prepw<<<KP, KP, 0, stream>>>(g0w, 360, 0, nullptr, nullptr, Wt0h, Wt0l, c0);

    k_gemm_mfma<true,false><<<2160, 256, 0, stream>>>(nf, nullptr, Wt0h, Wt0l, c0, g0b, rowsum, nullptr, nullptr, y0h, y0l, cs0, cq0);
    k_bnfin<<<1, 384, 0, stream>>>(cs0, cq0, bn0g, bn0b, 360, s0, h0);
    k_prepw<<<KP, KP, 0, stream>>>(g1w, 360, 0, s0, h0, Wt1h, Wt1l, c1);
    k_gemm_mfma<false,true><<<2160, 256, 0, stream>>>(y0h, y0l, Wt1h, Wt1l, c1, g1b, rowsum, s0, h0, y1h, y1l, cs1, cq1);
    k_bnfin<<<1, 384, 0, stream>>>(cs1, cq1, bn1g, bn1b, 360, s1, hh1);
    k_prepw<<<64, KP, 0, stream>>>(g2w1, 64, 0, s1, hh1, Wt2h, Wt2l, c2);
    k_prepw<<<16, KP, 0, stream>>>(scw, 16, 64, s1, hh1, Wt2h, Wt2l, c2);
    k_gemm2_mfma<<<720, 256, 0, stream>>>(y1h, y1l, Wt2h, Wt2l, c2, g2b1, scb, rowsum, h1buf, scbuf);
    k_stage2<<<1440, 256, 0, stream>>>(h1buf, scbuf, g2w2, g2b2, x2, cs2, cq2);
    k_bnfin<<<1, 64, 0, stream>>>(cs2, cq2, bn2g, bn2b, 16, s2, h2);
    k_qkv<<<BZ, 256, 0, stream>>>(x2, s2, h2, cls, wq, bq, wk, bk, wv, bv, qkv);
    k_attn<<<BZ*4*2, 256, 0, stream>>>(qkv, attn, obuf);
    k_pool<<<BZ, 256, 0, stream>>>(attn, obuf, wo, bo, f1w, f1b, f2w, f2b, f3w, f3b, out_sig, out_logits);
}